// Round 14
// baseline (739.842 us; speedup 1.0000x reference)
//
#include <hip/hip_runtime.h>
#include <float.h>

#define BB 32
#define MMv 512
#define LLv 512
#define DDv 128
#define HHv 8
#define DFFv 256
#define KNB 16
#define NLAY 2
#define NNODE (BB*MMv)       // 16384
#define TOTE  (NNODE*KNB)    // 262144 edges
#define WTOT  294912         // total transposed weight elements

typedef unsigned short ushort_t;
typedef unsigned int u32;
typedef __attribute__((ext_vector_type(8))) short bf16x8;
typedef __attribute__((ext_vector_type(4))) float f32x4;

__device__ __forceinline__ float bf2f(ushort_t u){
  union { u32 i; float f; } x; x.i = ((u32)u) << 16; return x.f;
}
__device__ __forceinline__ ushort_t f2bf(float f){
  union { u32 i; float f; } x; x.f = f;
  u32 r = x.i + 0x7FFFu + ((x.i >> 16) & 1u);   // RNE
  return (ushort_t)(r >> 16);
}
__device__ __forceinline__ float ldx(const void* p, size_t i, int f32){
  return f32 ? ((const float*)p)[i] : bf2f(((const ushort_t*)p)[i]);
}
__device__ __forceinline__ float wsum(float v){
  #pragma unroll
  for(int s=32;s;s>>=1) v += __shfl_xor(v,s);
  return v;
}

// ---- diagnostics (fp32 output) ----
__global__ __launch_bounds__(256) void diag_fill_k(float* out, int n, float val){
  for(int i = blockIdx.x*256 + threadIdx.x; i < n; i += gridDim.x*256) out[i] = val;
}

// ---- per-input dtype detection (one block per input) ----
struct P18 { const ushort_t* p[18]; int n[18]; };
__global__ __launch_bounds__(256) void ddet_k(P18 a, int* DF){
  int i = blockIdx.x;
  const ushort_t* q = a.p[i];
  int P = min(a.n[i], 4096);
  int t = threadIdx.x;
  int r1 = 0, evenNZ = 0, oddNZ = 0;
  for(int j=t; j<P; j+=256){
    ushort_t v = q[j];
    if(((v >> 7) & 0xFF) >= 0xC0) r1 = 1;   // impossible exponent for real bf16 data
    if(v){ if(j & 1) oddNZ = 1; else evenNZ = 1; }
  }
  __shared__ int sh[3];
  if(t==0){ sh[0]=0; sh[1]=0; sh[2]=0; }
  __syncthreads();
  if(r1) atomicOr(&sh[0],1);
  if(evenNZ) atomicOr(&sh[1],1);
  if(oddNZ) atomicOr(&sh[2],1);
  __syncthreads();
  if(t==0) DF[i] = sh[0] | ((sh[1]==0) & (sh[2]!=0));
}

// ---- weight prep: transpose + hi/lo split of all 14 weight slices, ONCE. ----
__global__ __launch_bounds__(256) void prep_k(const void* c1W, const void* c2W,
    const void* Wq, const void* Wk, const void* Wv, const void* Wo,
    const void* W1, const void* W2, ushort_t* Wth, ushort_t* Wtl, const int* DF){
  __shared__ ushort_t th[32][33];
  __shared__ ushort_t tl[32][33];
  int job = blockIdx.z;
  const void* src; int dfi; size_t soff, doff; int K, N;
  switch(job){
    case 0:  src=c1W; dfi=2;  soff=0; K=128; N=128; doff=0; break;
    case 1:  src=c2W; dfi=4;  soff=0; K=128; N=128; doff=16384; break;
    case 2: case 3:   // Wq layer 0,1 -> QKV block rows 0..127
      src=Wq; dfi=6; soff=(size_t)(job-2)*16384; K=128; N=128;
      doff=32768 + (size_t)(job-2)*49152; break;
    case 4: case 5:   // Wk -> QKV block rows 128..255
      src=Wk; dfi=7; soff=(size_t)(job-4)*16384; K=128; N=128;
      doff=32768 + (size_t)(job-4)*49152 + 16384; break;
    case 6: case 7:   // Wv -> QKV block rows 256..383
      src=Wv; dfi=8; soff=(size_t)(job-6)*16384; K=128; N=128;
      doff=32768 + (size_t)(job-6)*49152 + 32768; break;
    case 8: case 9:
      src=Wo; dfi=9; soff=(size_t)(job-8)*16384; K=128; N=128;
      doff=131072 + (size_t)(job-8)*16384; break;
    case 10: case 11:
      src=W1; dfi=10; soff=(size_t)(job-10)*32768; K=128; N=256;
      doff=163840 + (size_t)(job-10)*32768; break;
    default:
      src=W2; dfi=12; soff=(size_t)(job-12)*32768; K=256; N=128;
      doff=229376 + (size_t)(job-12)*32768; break;
  }
  int n0 = blockIdx.x*32, k0 = blockIdx.y*32;
  if(n0 >= N || k0 >= K) return;
  int f32 = DF[dfi];
  int tx = threadIdx.x, ty = threadIdx.y;   // 32 x 8
  #pragma unroll
  for(int i=0;i<4;i++){
    int k = k0+ty+8*i, n = n0+tx;
    float x = ldx(src, soff + (size_t)k*N + n, f32);
    ushort_t hi = f2bf(x);
    ushort_t lo = f2bf(x - bf2f(hi));
    th[ty+8*i][tx] = hi; tl[ty+8*i][tx] = lo;
  }
  __syncthreads();
  #pragma unroll
  for(int i=0;i<4;i++){
    int n = n0+ty+8*i, k = k0+tx;
    size_t d = doff + (size_t)n*K + k;
    Wth[d] = th[tx][ty+8*i];
    Wtl[d] = tl[tx][ty+8*i];
  }
}

// ---- split-transpose: x_enc[B,L,M] -> Xhi/Xlo[B,M,L] (x ~= hi+lo, ~2^-17 rel exact) ----
__global__ __launch_bounds__(256) void split_k(const void* xe, ushort_t* Xhi,
                                               ushort_t* Xlo, const int* DF){
  __shared__ ushort_t th[32][33];
  __shared__ ushort_t tl[32][33];
  int f32 = DF[1];
  int b = blockIdx.z;
  int m0 = blockIdx.x*32, l0 = blockIdx.y*32;
  int tx = threadIdx.x, ty = threadIdx.y;   // 32 x 8
  #pragma unroll
  for(int i=0;i<4;i++){
    int l = l0+ty+8*i, m = m0+tx;
    float x = ldx(xe, (size_t)b*LLv*MMv + (size_t)l*MMv + m, f32);
    ushort_t hi = f2bf(x);
    ushort_t lo = f2bf(x - bf2f(hi));
    th[ty+8*i][tx] = hi; tl[ty+8*i][tx] = lo;
  }
  __syncthreads();
  #pragma unroll
  for(int i=0;i<4;i++){
    size_t d = (size_t)b*MMv*LLv + (size_t)(m0+ty+8*i)*LLv + l0+tx;
    Xhi[d] = th[tx][ty+8*i];
    Xlo[d] = tl[tx][ty+8*i];
  }
}

// ---- per-(b,m) sum + rstd from transposed hi/lo rows: wave per row, coalesced ----
__global__ __launch_bounds__(256) void stats2_k(const ushort_t* Xhi, const ushort_t* Xlo,
                                                double* S64, double* R64){
  int row = blockIdx.x*4 + (threadIdx.x >> 6);
  int lane = threadIdx.x & 63;
  const ushort_t* Hr = Xhi + (size_t)row*LLv + lane*8;
  const ushort_t* Lr = Xlo + (size_t)row*LLv + lane*8;
  float s = 0.f, ss = 0.f;
  #pragma unroll
  for(int j=0;j<8;j++){
    float x = bf2f(Hr[j]) + bf2f(Lr[j]);
    s += x; ss = fmaf(x, x, ss);
  }
  s = wsum(s); ss = wsum(ss);
  if(lane == 0){
    S64[row] = (double)s;
    float cov = (ss - s*s*(1.0f/LLv)) * (1.0f/(LLv-1));
    float sd = (cov > 0.f) ? sqrtf(cov) : 0.f;
    R64[row] = (sd > 0.f) ? (double)(1.0f/sd) : 1.0;
  }
}

// ---- MFMA corr strip (split-bf16) + top-(K+1)-smallest selection.
// strip=16, 1024 threads, LDS overlay (Cs 33.0 KB reuses Ah/Al 33.3 KB):
// 2 blocks/CU (thread-limited), 32 waves/CU. Live set ~45 VGPR < 64 cap
// -> no scratch spill (round-12/13's strip=32 corr[16]+frags spilled
// ~110 B/thread). Each wave owns 32 n-cols (cs=0..1) and 1 selection row. ----
__global__ __launch_bounds__(1024, 8) void corrsel_k(const ushort_t* Xhi, const ushort_t* Xlo,
                                                     const double* S64, const double* R64,
                                                     int* nbr, const int* DF){
  __shared__ __attribute__((aligned(16))) char smem[33280];
  ushort_t* Ah = (ushort_t*)smem;            // 16*520 bf16
  ushort_t* Al = Ah + 16*520;                // 16*520 bf16
  float*    Cs = (float*)smem;               // 16*516 f32 (overlay, post-compute)
  int f32 = DF[1];
  // bijective swizzle: all 32 strips of a batch share lin%8 (same XCD)
  int lin = blockIdx.y*32 + blockIdx.x;     // 0..1023
  int xcd = lin & 7, slot = lin >> 3;       // slot 0..127
  int b = xcd + 8*(slot >> 5);              // b 0..31
  int strip = slot & 31;                    // 32 strips of 16 rows
  int m0 = strip*16;
  int t = threadIdx.x;
  int wave = t >> 6, lane = t & 63;         // 16 waves
  int quad = lane >> 4, l16 = lane & 15;
  const ushort_t* Hb = Xhi + (size_t)b*MMv*LLv;
  const ushort_t* Lb = Xlo + (size_t)b*MMv*LLv;
  {                                          // 16 rows x 64 chunks = 1024 threads
    int mm = t >> 6, c8 = (t & 63)*8;
    *(bf16x8*)&Ah[mm*520 + c8] = *(const bf16x8*)&Hb[(size_t)(m0+mm)*LLv + c8];
    *(bf16x8*)&Al[mm*520 + c8] = *(const bf16x8*)&Lb[(size_t)(m0+mm)*LLv + c8];
  }
  __syncthreads();
  const double* Sb = S64 + b*MMv;
  const double* Rb = R64 + b*MMv;
  int nbase = wave*32;                      // 16 waves x 32 cols = 512 n-columns
  float corr[8];                            // [cs][r], static-indexed
  #pragma unroll
  for(int cs=0; cs<2; cs++){
    int nn = nbase + cs*16 + l16;           // B row this lane streams
    size_t brow = (size_t)nn*LLv + quad*8;  // lane's K-offset folded in
    f32x4 acc = {0.f,0.f,0.f,0.f};
    if(f32){
      #pragma unroll
      for(int kk=0; kk<16; kk++){           // direct loads, minimal live set
        int ko = kk*32 + quad*8;
        bf16x8 bh = *(const bf16x8*)&Hb[brow + kk*32];
        bf16x8 bl = *(const bf16x8*)&Lb[brow + kk*32];
        bf16x8 ah = *(const bf16x8*)&Ah[l16*520 + ko];
        bf16x8 al = *(const bf16x8*)&Al[l16*520 + ko];
        acc = __builtin_amdgcn_mfma_f32_16x16x32_bf16(ah, bh, acc, 0, 0, 0);
        acc = __builtin_amdgcn_mfma_f32_16x16x32_bf16(ah, bl, acc, 0, 0, 0);
        acc = __builtin_amdgcn_mfma_f32_16x16x32_bf16(al, bh, acc, 0, 0, 0);
      }
    } else {
      #pragma unroll
      for(int g=0; g<4; g++){               // 4 groups x 4 K-steps
        bf16x8 bh[4];
        #pragma unroll
        for(int j=0;j<4;j++) bh[j] = *(const bf16x8*)&Hb[brow + g*128 + j*32];
        #pragma unroll
        for(int j=0;j<4;j++){
          int ko = g*128 + j*32 + quad*8;
          bf16x8 ah = *(const bf16x8*)&Ah[l16*520 + ko];
          acc = __builtin_amdgcn_mfma_f32_16x16x32_bf16(ah, bh[j], acc, 0, 0, 0);
        }
      }
    }
    float sn = (float)(Sb[nn]*(1.0/LLv));
    float rn = (float)Rb[nn];
    #pragma unroll
    for(int r=0;r<4;r++){
      int ml = quad*4 + r;                  // C/D: row = quad*4 + reg, col = lane&15
      float cov = (acc[r] - (float)Sb[m0+ml]*sn) * (1.0f/(LLv-1));
      corr[cs*4 + r] = cov * (float)Rb[m0+ml] * rn;
    }
  }
  __syncthreads();                          // all Ah/Al reads complete
  #pragma unroll
  for(int cs=0; cs<2; cs++){
    int nn = nbase + cs*16 + l16;
    #pragma unroll
    for(int r=0;r<4;r++){
      Cs[(quad*4 + r)*516 + nn] = corr[cs*4 + r];
    }
  }
  __syncthreads();
  // each wave owns 1 row; selection in-wave only, all-register vals[]
  {
    int r = wave;
    float vals[8];
    #pragma unroll
    for(int j=0;j<8;j++) vals[j] = Cs[r*516 + lane + 64*j];
    for(int it=0; it<=KNB; it++){
      float bvv = FLT_MAX; int bi = 0x7fffffff;
      #pragma unroll
      for(int j=0;j<8;j++){
        int n = lane + 64*j;
        if(vals[j] < bvv){ bvv = vals[j]; bi = n; }
      }
      // butterfly (min value, tie -> min index) over 64 lanes
      #pragma unroll
      for(int s=32; s; s>>=1){
        float v2 = __shfl_xor(bvv, s);
        int   i2 = __shfl_xor(bi,  s);
        if(v2 < bvv || (v2 == bvv && i2 < bi)){ bvv = v2; bi = i2; }
      }
      int gbi = bi;                          // uniform across the wave
      int bic = min(max(gbi, 0), MMv-1);     // clamp: bad data -> wrong answer, never a fault
      if(it > 0 && lane == 0) nbr[(size_t)(b*MMv + m0 + r)*KNB + it-1] = bic;
      if((gbi & 63) == lane && gbi < MMv){
        int jj = gbi >> 6;                   // static-index clear: stays in VGPRs
        #pragma unroll
        for(int j=0;j<8;j++) if(j == jj) vals[j] = FLT_MAX;
      }
    }
  }
}

// ---- graph build (all data-dependent indices clamped) ----
__global__ __launch_bounds__(256) void zero_k(int* p){
  p[blockIdx.x*256 + threadIdx.x] = 0;
}

__global__ __launch_bounds__(256) void hist_k(const int* nbr, int* cnt){
  int tid = blockIdx.x*256 + threadIdx.x;
  int b = tid >> 13;
  int col = min(max(nbr[tid], 0), MMv-1);
  atomicAdd(&cnt[b*MMv + col], 1);
}

__global__ __launch_bounds__(256) void scan_k(const int* cnt, int* off,
                                              int* cursor, float* dinv){
  __shared__ int part[256];
  int t = threadIdx.x;
  int base = t*64, s = 0;
  for(int i=0;i<64;i++) s += cnt[base+i];
  part[t] = s; __syncthreads();
  for(int st=1; st<256; st<<=1){
    int v = (t >= st) ? part[t-st] : 0;
    __syncthreads();
    part[t] += v; __syncthreads();
  }
  int run = (t > 0) ? part[t-1] : 0;
  for(int i=0;i<64;i++){
    int idx = base+i;
    off[idx] = run; cursor[idx] = run;
    run += cnt[idx];
    dinv[idx] = 1.0f/sqrtf((float)(cnt[idx]+1));   // +1 self loop
  }
  if(t == 255) off[NNODE] = run;
}

__global__ __launch_bounds__(256) void fill_k(const int* nbr, int* cursor, int* esrc){
  int tid = blockIdx.x*256 + threadIdx.x;   // edge: b*8192 + e, e = m*16+k
  int b = tid >> 13;
  int rem = tid & 8191;
  int col = min(max(nbr[tid], 0), MMv-1);
  int dst = b*MMv + col;
  int srcl = rem & 511;                      // src = e mod 512 (faithful tile() quirk)
  int pos = atomicAdd(&cursor[dst], 1);
  pos = min(max(pos, 0), TOTE-1);
  esrc[pos] = b*MMv + srcl;
}

// ---- split-bf16 MFMA GEMM: C = A*Wt^T (+bias)(+relu). BM=64, BN=32. ----
__global__ __launch_bounds__(256) void gemm_k(const float* A,
                                              const ushort_t* Wth, const ushort_t* Wtl,
                                              size_t woffT, int wdi,
                                              const void* bias, int boff, int bdi,
                                              float* C, int Kd, int Dout, int relu,
                                              const int* DF){
  __shared__ __attribute__((aligned(16))) ushort_t Ah[64*72];
  __shared__ __attribute__((aligned(16))) ushort_t Al[64*72];
  __shared__ __attribute__((aligned(16))) ushort_t Wh[32*72];
  __shared__ __attribute__((aligned(16))) ushort_t Wl[32*72];
  int wf32 = DF[wdi];
  int bf32 = DF[bdi];
  int m0 = blockIdx.y*64, n0 = blockIdx.x*32;
  int t = threadIdx.x;
  int wave = t >> 6, lane = t & 63;
  int quad = lane >> 4, l16 = lane & 15;
  f32x4 acc[2];
  #pragma unroll
  for(int nt=0;nt<2;nt++) acc[nt] = (f32x4){0.f,0.f,0.f,0.f};
  for(int kc=0; kc<Kd; kc+=64){
    for(int s=t; s<1024; s+=256){           // A: 64 rows x 16 float4
      int row = s >> 4, c4 = (s & 15)*4;
      float4 av = *(const float4*)&A[(size_t)(m0+row)*Kd + kc + c4];
      ushort_t h0=f2bf(av.x), h1=f2bf(av.y), h2=f2bf(av.z), h3=f2bf(av.w);
      ushort_t g0=f2bf(av.x-bf2f(h0)), g1=f2bf(av.y-bf2f(h1));
      ushort_t g2=f2bf(av.z-bf2f(h2)), g3=f2bf(av.w-bf2f(h3));
      *(ushort4*)&Ah[row*72 + c4] = make_ushort4(h0,h1,h2,h3);
      *(ushort4*)&Al[row*72 + c4] = make_ushort4(g0,g1,g2,g3);
    }
    for(int s=t; s<256; s+=256){            // W^T: 32 rows x 8 ushort8
      int row = s >> 3, c8 = (s & 7)*8;
      size_t g = woffT + (size_t)(n0+row)*Kd + kc + c8;
      *(bf16x8*)&Wh[row*72 + c8] = *(const bf16x8*)&Wth[g];
      if(wf32) *(bf16x8*)&Wl[row*72 + c8] = *(const bf16x8*)&Wtl[g];
    }
    __syncthreads();
    #pragma unroll
    for(int kk=0; kk<64; kk+=32){
      int ko = kk + quad*8;
      bf16x8 ah = *(const bf16x8*)&Ah[(wave*16+l16)*72 + ko];
      bf16x8 al = *(const bf16x8*)&Al[(wave*16+l16)*72 + ko];
      #pragma unroll
      for(int nt=0; nt<2; nt++){
        bf16x8 wh = *(const bf16x8*)&Wh[(nt*16+l16)*72 + ko];
        acc[nt] = __builtin_amdgcn_mfma_f32_16x16x32_bf16(ah, wh, acc[nt], 0, 0, 0);
        acc[nt] = __builtin_amdgcn_mfma_f32_16x16x32_bf16(al, wh, acc[nt], 0, 0, 0);
        if(wf32){
          bf16x8 wl = *(const bf16x8*)&Wl[(nt*16+l16)*72 + ko];
          acc[nt] = __builtin_amdgcn_mfma_f32_16x16x32_bf16(ah, wl, acc[nt], 0, 0, 0);
        }
      }
    }
    __syncthreads();
  }
  #pragma unroll
  for(int nt=0; nt<2; nt++){
    int n = n0 + nt*16 + l16;
    float bv = bias ? ldx(bias, boff + n, bf32) : 0.f;
    #pragma unroll
    for(int r=0; r<2*2; r++){
      float v = acc[nt][r] + bv;              // C/D: row = quad*4+r, col = l16
      if(relu) v = fmaxf(v, 0.f);
      C[(size_t)(m0 + wave*16 + quad*4 + r)*Dout + n] = v;
    }
  }
}

// ---- fused QKV projection, BN=32: grid (12,256).
// n0<128: Q = hF x Wq -> t0[.,128]; else K/V = xg x W(kv) -> kv[.,256]. ----
__global__ __launch_bounds__(256) void qkv_k(const float* hF, const float* xg,
                                             const ushort_t* Wth, const ushort_t* Wtl,
                                             size_t qoff, float* t0, float* kv,
                                             const int* DF){
  __shared__ __attribute__((aligned(16))) ushort_t Ah[64*72];
  __shared__ __attribute__((aligned(16))) ushort_t Al[64*72];
  __shared__ __attribute__((aligned(16))) ushort_t Wh[32*72];
  __shared__ __attribute__((aligned(16))) ushort_t Wl[32*72];
  int m0 = blockIdx.y*64, n0 = blockIdx.x*32;   // n0 in [0,384)
  int wdi = (n0 < 128) ? 6 : ((n0 < 256) ? 7 : 8);
  int wf32 = DF[wdi];
  const float* A = (n0 < 128) ? hF : xg;
  int t = threadIdx.x;
  int wave = t >> 6, lane = t & 63;
  int quad = lane >> 4, l16 = lane & 15;
  f32x4 acc[2];
  #pragma unroll
  for(int nt=0;nt<2;nt++) acc[nt] = (f32x4){0.f,0.f,0.f,0.f};
  for(int kc=0; kc<DDv; kc+=64){
    for(int s=t; s<1024; s+=256){
      int row = s >> 4, c4 = (s & 15)*4;
      float4 av = *(const float4*)&A[(size_t)(m0+row)*DDv + kc + c4];
      ushort_t h0=f2bf(av.x), h1=f2bf(av.y), h2=f2bf(av.z), h3=f2bf(av.w);
      ushort_t g0=f2bf(av.x-bf2f(h0)), g1=f2bf(av.y-bf2f(h1));
      ushort_t g2=f2bf(av.z-bf2f(h2)), g3=f2bf(av.w-bf2f(h3));
      *(ushort4*)&Ah[row*72 + c4] = make_ushort4(h0,h1,h2,h3);
      *(ushort4*)&Al[row*72 + c4] = make_ushort4(g0,g1,g2,g3);
    }
    for(int s=t; s<256; s+=256){
      int row = s >> 3, c8 = (s & 7)*8;
      size_t g = qoff + (size_t)(n0+row)*DDv + kc + c8;
      *(bf16x8*)&Wh[row*72 + c8] = *(const bf16x8*)&Wth[g];
      if(wf32) *(bf16x8*)&Wl[row*72 + c8] = *(const bf16x8*)&Wtl[g];
    }
    __syncthreads();
    #pragma unroll
    for(int kk=0; kk<64; kk+=32){
      int ko = kk + quad*8;
      bf16x8 ah = *(const bf16x8*)&Ah[(wave*16+l16)*72 + ko];
      bf16x8 al = *(const bf16x8*)&Al[(wave*16+l16)*72 + ko];
      #pragma unroll
      for(int nt=0; nt<2; nt++){
        bf16x8 wh = *(const bf16x8*)&Wh[(nt*16+l16)*72 + ko];
        acc[nt] = __builtin_amdgcn_mfma_f32_16x16x32_bf16(ah, wh, acc[nt], 0, 0, 0);
        acc[nt] = __builtin_amdgcn_mfma_f32_16x16x32_bf16(al, wh, acc[nt], 0, 0, 0);
        if(wf32){
          bf16x8 wl = *(const bf16x8*)&Wl[(nt*16+l16)*72 + ko];
          acc[nt] = __builtin_amdgcn_mfma_f32_16x16x32_bf16(ah, wl, acc[nt], 0, 0, 0);
        }
      }
    }
    __syncthreads();
  }
  float* C = (n0 < 128) ? t0 : kv;
  int ldC = (n0 < 128) ? 128 : 256;
  int nb  = (n0 < 128) ? n0 : (n0 - 128);
  #pragma unroll
  for(int nt=0; nt<2; nt++){
    int n = nb + nt*16 + l16;
    #pragma unroll
    for(int r=0; r<4; r++){
      C[(size_t)(m0 + wave*16 + quad*4 + r)*ldC + n] = acc[nt][r];
    }
  }
}

// ---- GCN aggregation: 4x-unrolled gather ----
__global__ __launch_bounds__(256) void agg_k(const float* xw, const int* off,
                                             const int* esrc, const float* dinv,
                                             const void* bias, int bdi, float* out,
                                             const int* DF){
  int f32 = DF[bdi];
  int node = blockIdx.x*4 + (threadIdx.x >> 6);
  int lane = threadIdx.x & 63;
  float dn = dinv[node];
  float2 xv = ((const float2*)(xw + (size_t)node*DDv))[lane];
  float a0 = dn*dn*xv.x;
  float a1 = dn*dn*xv.y;
  int e0 = min(max(off[node], 0), TOTE);
  int e1 = min(max(off[node+1], e0), TOTE);
  int e = e0;
  for(; e + 4 <= e1; e += 4){
    int s0 = min(max(esrc[e+0], 0), NNODE-1);
    int s1 = min(max(esrc[e+1], 0), NNODE-1);
    int s2 = min(max(esrc[e+2], 0), NNODE-1);
    int s3 = min(max(esrc[e+3], 0), NNODE-1);
    float2 v0 = ((const float2*)(xw + (size_t)s0*DDv))[lane];
    float2 v1 = ((const float2*)(xw + (size_t)s1*DDv))[lane];
    float2 v2 = ((const float2*)(xw + (size_t)s2*DDv))[lane];
    float2 v3 = ((const float2*)(xw + (size_t)s3*DDv))[lane];
    float w0 = dinv[s0]*dn, w1 = dinv[s1]*dn, w2 = dinv[s2]*dn, w3 = dinv[s3]*dn;
    a0 = fmaf(w0, v0.x, a0); a1 = fmaf(w0, v0.y, a1);
    a0 = fmaf(w1, v1.x, a0); a1 = fmaf(w1, v1.y, a1);
    a0 = fmaf(w2, v2.x, a0); a1 = fmaf(w2, v2.y, a1);
    a0 = fmaf(w3, v3.x, a0); a1 = fmaf(w3, v3.y, a1);
  }
  for(; e < e1; e++){
    int s = min(max(esrc[e], 0), NNODE-1);
    float w = dinv[s]*dn;
    float2 sv = ((const float2*)(xw + (size_t)s*DDv))[lane];
    a0 = fmaf(w, sv.x, a0);
    a1 = fmaf(w, sv.y, a1);
  }
  a0 += ldx(bias, 2*lane, f32); a1 += ldx(bias, 2*lane+1, f32);
  ((float2*)(out + (size_t)node*DDv))[lane] = make_float2(fmaxf(a0,0.f), fmaxf(a1,0.f));
}

// ---- cross-attention, split-K flash: 1024 threads, exact two-state merge. ----
__global__ __launch_bounds__(1024) void attn_k(const float* qg, const float* kv,
                                               float* og){
  __shared__ float Ks[512*16];
  __shared__ float Vs[512*16];
  int bh = blockIdx.x;
  int b = bh >> 3, hh = bh & 7;
  size_t baseq = (size_t)b*MMv*DDv + (size_t)hh*16;
  size_t basekv = (size_t)b*MMv*256 + (size_t)hh*16;
  int t = threadIdx.x;
  for(int idx=t; idx<2048; idx+=1024){       // 512 rows x 4 float4
    int kk = idx >> 2, i4 = (idx & 3)*4;
    ((float4*)Ks)[idx] = *(const float4*)&kv[basekv + (size_t)kk*256 + i4];
    ((float4*)Vs)[idx] = *(const float4*)&kv[basekv + (size_t)kk*256 + 128 + i4];
  }
  __syncthreads();
  int r = t & 511, g = t >> 9;
  float qr[16];
  #pragma unroll
  for(int i4=0;i4<4;i4++){
    float4 qv = *(const float4*)&qg[baseq + (size_t)r*DDv + i4*4];
    qr[i4*4+0]=qv.x; qr[i4*4+1]=qv.y; qr[i4*4+2]=qv.z; qr[i4*4+3]=qv.w;
  }
  float m = -FLT_MAX, l = 0.f;
  float acc[16] = {};
  int k0 = g*256;
  for(int kk=k0; kk<k0+256; kk++){
    const float* kp = &Ks[kk*16];
    float s = 0.f;
    #pragma unroll
    for(int i=0;i<16;i++) s = fmaf(qr[i], kp[i], s);
    s *= 0.25f;
    if(s > m){                               // rare after warm-up
      float c = __expf(m - s);
      l *= c;
      #pragma unroll
      for(int i=0;i<16;i++) acc[i] *= c;
      m = s;
    }
    float p = __expf(s - m);
    l += p;
    const float* vp = &Vs[kk*16];
    #pragma unroll
    for(int i=0;i<16;i++) acc[i] = fmaf(p, vp[i], acc[i]);
  }
  __syncthreads();                           // K/V consumption complete
  if(g == 1){                                // publish partial state
    #pragma unroll
    for(int i=0;i<16;i++) Ks[r*16 + i] = acc[i];
    Vs[r] = m; Vs[512 + r] = l;
  }
  __syncthreads();
  if(g == 0){                                // exact two-state merge
    float m1 = Vs[r], l1 = Vs[512 + r];
    float M = fmaxf(m, m1);
    float c0 = __expf(m - M), c1 = __expf(m1 - M);
    float inv = 1.0f/(l*c0 + l1*c1);
    #pragma unroll
    for(int i=0;i<16;i++)
      og[baseq + (size_t)r*DDv + i] = (acc[i]*c0 + Ks[r*16 + i]*c1)*inv;
  }
}

// ---- residual + LayerNorm: wave per row, shuffle-reduced, fp32 ----
__global__ __launch_bounds__(256) void ln_k(const float* h, const float* delta,
                                            const void* g, int gdi, const void* bb, int bdi, int po,
                                            float* dst, const int* DF){
  int gf32 = DF[gdi], bf32 = DF[bdi];
  int row = blockIdx.x*4 + (threadIdx.x >> 6);
  int lane = threadIdx.x & 63;
  const float2* hr = (const float2*)(h + (size_t)row*DDv);
  const float2* dr = (const float2*)(delta + (size_t)row*DDv);
  float2 hv = hr[lane], dv = dr[lane];
  float x0 = hv.x + dv.x, x1 = hv.y + dv.y;
  float mu = wsum(x0 + x1) * (1.0f/DDv);
  float d0 = x0 - mu, d1 = x1 - mu;
  float var = wsum(d0*d0 + d1*d1) * (1.0f/DDv);
  float rs = 1.0f/sqrtf(var + 1e-5f);
  int c0 = lane*2;
  float y0 = d0*rs*ldx(g, po+c0,   gf32) + ldx(bb, po+c0,   bf32);
  float y1 = d1*rs*ldx(g, po+c0+1, gf32) + ldx(bb, po+c0+1, bf32);
  ((float2*)(dst + (size_t)row*DDv))[lane] = make_float2(y0, y1);
}

// ---- enc -> fp32 h ----
__global__ __launch_bounds__(256) void cvt_k(const void* in, float* out, const int* DF){
  int f32 = DF[0];
  int tid = blockIdx.x*256 + threadIdx.x;
  out[tid] = ldx(in, tid, f32);
}

extern "C" void kernel_launch(void* const* d_in, const int* in_sizes, int n_in,
                              void* d_out, int out_size, void* d_ws, size_t ws_size,
                              hipStream_t stream) {
  if(n_in != 18){
    diag_fill_k<<<256, 256, 0, stream>>>((float*)d_out, out_size, 1000.0f);
    return;
  }
  const int expect[18] = {
    BB*MMv*DDv, BB*LLv*MMv, DDv*DDv, DDv, DDv*DDv, DDv,
    NLAY*DDv*DDv, NLAY*DDv*DDv, NLAY*DDv*DDv, NLAY*DDv*DDv,
    NLAY*DDv*DFFv, NLAY*DFFv, NLAY*DFFv*DDv, NLAY*DDv,
    NLAY*DDv, NLAY*DDv, NLAY*DDv, NLAY*DDv
  };
  for(int i=0;i<18;i++){
    if(in_sizes[i] != expect[i]){
      diag_fill_k<<<256, 256, 0, stream>>>((float*)d_out, out_size, 2000.0f + 10.0f*i);
      return;
    }
  }

  const void* enc  = d_in[0];
  const void* xe   = d_in[1];
  const void* c1W  = d_in[2];
  const void* c1b  = d_in[3];
  const void* c2W  = d_in[4];
  const void* c2b  = d_in[5];
  const void* Wq   = d_in[6];
  const void* Wk   = d_in[7];
  const void* Wv   = d_in[8];
  const void* Wo   = d_in[9];
  const void* W1   = d_in[10];
  const void* b1   = d_in[11];
  const void* W2   = d_in[12];
  const void* b2   = d_in[13];
  const void* ln1g = d_in[14];
  const void* ln1b = d_in[15];
  const void* ln2g = d_in[16];
  const void* ln2b = d_in[17];

  char* ws = (char*)d_ws;
  size_t o = 0;
  auto alloc = [&](size_t bytes){ size_t r = o; o = (o + bytes + 255) & ~(size_t)255; return r; };
  double* S64  = (double*)(ws + alloc((size_t)NNODE*8));
  double* R64  = (double*)(ws + alloc((size_t)NNODE*8));
  float* dinv  = (float*)(ws + alloc((size_t)NNODE*4));
  int*   cnt   = (int*)  (ws + alloc((size_t)NNODE*4));
  int*   cursor= (int*)  (ws + alloc((size_t)NNODE*4));
  int*   off   = (int*)  (ws + alloc((size_t)(NNODE+1)*4));
  int*   nbr   = (int*)  (ws + alloc((size_t)TOTE*4));
  int*   esrc  = (int*)  (ws + alloc((size_t)TOTE*4));
  int*   DF    = (int*)  (ws + alloc(256));
  ushort_t* Wth = (ushort_t*)(ws + alloc((size_t)WTOT*2));
  ushort_t* Wtl = (ushort_t*)(ws + alloc((size_t)WTOT*2));
  const size_t ACTF = (size_t)NNODE*DDv*4;   // fp32 activation: 8.39 MB
  float* hF = (float*)(ws + alloc(ACTF));
  float* xg = (float*)(ws + alloc(ACTF));
  float* t0 = (float*)(ws + alloc(ACTF));
  float* t1 = (float*)(ws + alloc(ACTF));
  float* t2 = (float*)(ws + alloc(ACTF));    // t1+t2 contiguous: kv[NNODE][256] / ffn hidden
  float* t3 = (float*)(ws + alloc(ACTF));
  float* kv = t1;                             // 16.78 MB span
  float* fb = t1;                             // ffn hidden; kv dead when ffn runs
  // Xhi/Xlo (graph phase only) overlay hF..t1 — consumed by corrsel before cvt_k writes hF
  ushort_t* Xhi = (ushort_t*)hF;
  ushort_t* Xlo = Xhi + (size_t)BB*MMv*LLv;   // 16.78 MB each
  if(ws_size < o){
    diag_fill_k<<<256, 256, 0, stream>>>((float*)d_out, out_size, 3000.0f);
    return;
  }

  // ---- per-input dtype detection + weight transpose/split prep ----
  P18 pack;
  for(int i=0;i<18;i++){ pack.p[i] = (const ushort_t*)d_in[i]; pack.n[i] = in_sizes[i]; }
  ddet_k<<<18, 256, 0, stream>>>(pack, DF);
  prep_k<<<dim3(8,8,14), dim3(32,8), 0, stream>>>(c1W, c2W, Wq, Wk, Wv, Wo, W1, W2,
                                                  Wth, Wtl, DF);

  // --- graph construction (split-bf16 MFMA corr + hi/lo stats + selection) ---
  split_k<<<dim3(16,16,BB), dim3(32,8), 0, stream>>>(xe, Xhi, Xlo, DF);
  stats2_k<<<NNODE/4, 256, 0, stream>>>(Xhi, Xlo, S64, R64);
  corrsel_k<<<dim3(32, BB), 1024, 0, stream>>>(Xhi, Xlo, S64, R64, nbr, DF);
  zero_k<<<NNODE/256, 256, 0, stream>>>(cnt);
  hist_k<<<TOTE/256, 256, 0, stream>>>(nbr, cnt);
  scan_k<<<1, 256, 0, stream>>>(cnt, off, cursor, dinv);
  fill_k<<<TOTE/256, 256, 0, stream>>>(nbr, cursor, esrc);

  // --- GCN (2 layers, fp32 activations, MFMA gemms) ---
  cvt_k<<<NNODE*DDv/256, 256, 0, stream>>>(enc, hF, DF);
  gemm_k<<<dim3(4,256), 256, 0, stream>>>(hF, Wth, Wtl, 0, 2, nullptr, 0, 3, t0, DDv, DDv, 0, DF);
  agg_k<<<NNODE/4, 256, 0, stream>>>(t0, off, esrc, dinv, c1b, 3, t1, DF);
  gemm_k<<<dim3(4,256), 256, 0, stream>>>(t1, Wth, Wtl, 16384, 4, nullptr, 0, 5, t0, DDv, DDv, 0, DF);
  agg_k<<<NNODE/4, 256, 0, stream>>>(t0, off, esrc, dinv, c2b, 5, xg, DF);

  // --- transformer (2 layers; query stream = hF, kv = xg) ---
  for(int l=0; l<NLAY; l++){
    qkv_k<<<dim3(12,256), 256, 0, stream>>>(hF, xg, Wth, Wtl,
                                            32768 + (size_t)l*49152, t0, kv, DF);
    attn_k<<<BB*HHv, 1024, 0, stream>>>(t0, kv, t3);
    gemm_k<<<dim3(4,256), 256, 0, stream>>>(t3, Wth, Wtl, 131072 + (size_t)l*16384, 9, nullptr, 0, 9, t0, DDv, DDv, 0, DF);
    ln_k<<<NNODE/4, 256, 0, stream>>>(hF, t0, ln1g, 14, ln1b, 15, l*DDv, hF, DF);
    gemm_k<<<dim3(8,256), 256, 0, stream>>>(hF, Wth, Wtl, 163840 + (size_t)l*32768, 10, b1, l*DFFv, 11, fb, DDv, DFFv, 1, DF);
    gemm_k<<<dim3(4,256), 256, 0, stream>>>(fb, Wth, Wtl, 229376 + (size_t)l*32768, 12, b2, l*DDv, 13, t0, DFFv, DDv, 0, DF);
    float* dst = (l == NLAY-1) ? (float*)d_out : hF;
    ln_k<<<NNODE/4, 256, 0, stream>>>(hF, t0, ln2g, 16, ln2b, 17, l*DDv, dst, DF);
  }
}

// Round 15
// 717.269 us; speedup vs baseline: 1.0315x; 1.0315x over previous
//
#include <hip/hip_runtime.h>
#include <float.h>

#define BB 32
#define MMv 512
#define LLv 512
#define DDv 128
#define HHv 8
#define DFFv 256
#define KNB 16
#define NLAY 2
#define NNODE (BB*MMv)       // 16384
#define TOTE  (NNODE*KNB)    // 262144 edges
#define WTOT  294912         // total transposed weight elements

typedef unsigned short ushort_t;
typedef unsigned int u32;
typedef __attribute__((ext_vector_type(8))) short bf16x8;
typedef __attribute__((ext_vector_type(4))) float f32x4;

__device__ __forceinline__ float bf2f(ushort_t u){
  union { u32 i; float f; } x; x.i = ((u32)u) << 16; return x.f;
}
__device__ __forceinline__ ushort_t f2bf(float f){
  union { u32 i; float f; } x; x.f = f;
  u32 r = x.i + 0x7FFFu + ((x.i >> 16) & 1u);   // RNE
  return (ushort_t)(r >> 16);
}
__device__ __forceinline__ float ldx(const void* p, size_t i, int f32){
  return f32 ? ((const float*)p)[i] : bf2f(((const ushort_t*)p)[i]);
}
__device__ __forceinline__ float wsum(float v){
  #pragma unroll
  for(int s=32;s;s>>=1) v += __shfl_xor(v,s);
  return v;
}

// ---- diagnostics (fp32 output) ----
__global__ __launch_bounds__(256) void diag_fill_k(float* out, int n, float val){
  for(int i = blockIdx.x*256 + threadIdx.x; i < n; i += gridDim.x*256) out[i] = val;
}

// ---- per-input dtype detection (one block per input) ----
struct P18 { const ushort_t* p[18]; int n[18]; };
__global__ __launch_bounds__(256) void ddet_k(P18 a, int* DF){
  int i = blockIdx.x;
  const ushort_t* q = a.p[i];
  int P = min(a.n[i], 4096);
  int t = threadIdx.x;
  int r1 = 0, evenNZ = 0, oddNZ = 0;
  for(int j=t; j<P; j+=256){
    ushort_t v = q[j];
    if(((v >> 7) & 0xFF) >= 0xC0) r1 = 1;   // impossible exponent for real bf16 data
    if(v){ if(j & 1) oddNZ = 1; else evenNZ = 1; }
  }
  __shared__ int sh[3];
  if(t==0){ sh[0]=0; sh[1]=0; sh[2]=0; }
  __syncthreads();
  if(r1) atomicOr(&sh[0],1);
  if(evenNZ) atomicOr(&sh[1],1);
  if(oddNZ) atomicOr(&sh[2],1);
  __syncthreads();
  if(t==0) DF[i] = sh[0] | ((sh[1]==0) & (sh[2]!=0));
}

// ---- weight prep: transpose + hi/lo split of all 14 weight slices, ONCE. ----
__global__ __launch_bounds__(256) void prep_k(const void* c1W, const void* c2W,
    const void* Wq, const void* Wk, const void* Wv, const void* Wo,
    const void* W1, const void* W2, ushort_t* Wth, ushort_t* Wtl, const int* DF){
  __shared__ ushort_t th[32][33];
  __shared__ ushort_t tl[32][33];
  int job = blockIdx.z;
  const void* src; int dfi; size_t soff, doff; int K, N;
  switch(job){
    case 0:  src=c1W; dfi=2;  soff=0; K=128; N=128; doff=0; break;
    case 1:  src=c2W; dfi=4;  soff=0; K=128; N=128; doff=16384; break;
    case 2: case 3:   // Wq layer 0,1 -> QKV block rows 0..127
      src=Wq; dfi=6; soff=(size_t)(job-2)*16384; K=128; N=128;
      doff=32768 + (size_t)(job-2)*49152; break;
    case 4: case 5:   // Wk -> QKV block rows 128..255
      src=Wk; dfi=7; soff=(size_t)(job-4)*16384; K=128; N=128;
      doff=32768 + (size_t)(job-4)*49152 + 16384; break;
    case 6: case 7:   // Wv -> QKV block rows 256..383
      src=Wv; dfi=8; soff=(size_t)(job-6)*16384; K=128; N=128;
      doff=32768 + (size_t)(job-6)*49152 + 32768; break;
    case 8: case 9:
      src=Wo; dfi=9; soff=(size_t)(job-8)*16384; K=128; N=128;
      doff=131072 + (size_t)(job-8)*16384; break;
    case 10: case 11:
      src=W1; dfi=10; soff=(size_t)(job-10)*32768; K=128; N=256;
      doff=163840 + (size_t)(job-10)*32768; break;
    default:
      src=W2; dfi=12; soff=(size_t)(job-12)*32768; K=256; N=128;
      doff=229376 + (size_t)(job-12)*32768; break;
  }
  int n0 = blockIdx.x*32, k0 = blockIdx.y*32;
  if(n0 >= N || k0 >= K) return;
  int f32 = DF[dfi];
  int tx = threadIdx.x, ty = threadIdx.y;   // 32 x 8
  #pragma unroll
  for(int i=0;i<4;i++){
    int k = k0+ty+8*i, n = n0+tx;
    float x = ldx(src, soff + (size_t)k*N + n, f32);
    ushort_t hi = f2bf(x);
    ushort_t lo = f2bf(x - bf2f(hi));
    th[ty+8*i][tx] = hi; tl[ty+8*i][tx] = lo;
  }
  __syncthreads();
  #pragma unroll
  for(int i=0;i<4;i++){
    int n = n0+ty+8*i, k = k0+tx;
    size_t d = doff + (size_t)n*K + k;
    Wth[d] = th[tx][ty+8*i];
    Wtl[d] = tl[tx][ty+8*i];
  }
}

// ---- split-transpose: x_enc[B,L,M] -> Xhi/Xlo[B,M,L] (x ~= hi+lo, ~2^-17 rel exact) ----
__global__ __launch_bounds__(256) void split_k(const void* xe, ushort_t* Xhi,
                                               ushort_t* Xlo, const int* DF){
  __shared__ ushort_t th[32][33];
  __shared__ ushort_t tl[32][33];
  int f32 = DF[1];
  int b = blockIdx.z;
  int m0 = blockIdx.x*32, l0 = blockIdx.y*32;
  int tx = threadIdx.x, ty = threadIdx.y;   // 32 x 8
  #pragma unroll
  for(int i=0;i<4;i++){
    int l = l0+ty+8*i, m = m0+tx;
    float x = ldx(xe, (size_t)b*LLv*MMv + (size_t)l*MMv + m, f32);
    ushort_t hi = f2bf(x);
    ushort_t lo = f2bf(x - bf2f(hi));
    th[ty+8*i][tx] = hi; tl[ty+8*i][tx] = lo;
  }
  __syncthreads();
  #pragma unroll
  for(int i=0;i<4;i++){
    size_t d = (size_t)b*MMv*LLv + (size_t)(m0+ty+8*i)*LLv + l0+tx;
    Xhi[d] = th[tx][ty+8*i];
    Xlo[d] = tl[tx][ty+8*i];
  }
}

// ---- per-(b,m) sum + rstd from transposed hi/lo rows: wave per row, coalesced ----
__global__ __launch_bounds__(256) void stats2_k(const ushort_t* Xhi, const ushort_t* Xlo,
                                                double* S64, double* R64){
  int row = blockIdx.x*4 + (threadIdx.x >> 6);
  int lane = threadIdx.x & 63;
  const ushort_t* Hr = Xhi + (size_t)row*LLv + lane*8;
  const ushort_t* Lr = Xlo + (size_t)row*LLv + lane*8;
  float s = 0.f, ss = 0.f;
  #pragma unroll
  for(int j=0;j<8;j++){
    float x = bf2f(Hr[j]) + bf2f(Lr[j]);
    s += x; ss = fmaf(x, x, ss);
  }
  s = wsum(s); ss = wsum(ss);
  if(lane == 0){
    S64[row] = (double)s;
    float cov = (ss - s*s*(1.0f/LLv)) * (1.0f/(LLv-1));
    float sd = (cov > 0.f) ? sqrtf(cov) : 0.f;
    R64[row] = (sd > 0.f) ? (double)(1.0f/sd) : 1.0;
  }
}

// ---- MFMA corr strip (split-bf16) + top-(K+1)-smallest selection.
// ROUND-13 OPTIMUM (empirically bracketed): strip=32, 1024 threads, LDS
// overlay (66.6 KB -> 2 blocks/CU, ~77% occ), direct B loads, fan-out 6.
// The (1024,8) VGPR cap induces ~110B/thread scratch spill — measured
// FASTER (123us) than spill-free fan-out-3 (149us) or no-overlay (135us). ----
__global__ __launch_bounds__(1024, 8) void corrsel_k(const ushort_t* Xhi, const ushort_t* Xlo,
                                                     const double* S64, const double* R64,
                                                     int* nbr, const int* DF){
  __shared__ __attribute__((aligned(16))) char smem[66560];
  ushort_t* Ah = (ushort_t*)smem;            // 32*520 bf16
  ushort_t* Al = Ah + 32*520;                // 32*520 bf16
  float*    Cs = (float*)smem;               // 32*516 f32 (overlay, post-compute)
  int f32 = DF[1];
  // bijective swizzle: all 16 strips of a batch share lin%8 (same XCD)
  int lin = blockIdx.y*16 + blockIdx.x;     // 0..511
  int xcd = lin & 7, slot = lin >> 3;       // slot 0..63
  int b = xcd + 8*(slot >> 4);              // b 0..31
  int strip = slot & 15;                    // 16 strips of 32 rows
  int m0 = strip*32;
  int t = threadIdx.x;
  int wave = t >> 6, lane = t & 63;         // 16 waves
  int quad = lane >> 4, l16 = lane & 15;
  const ushort_t* Hb = Xhi + (size_t)b*MMv*LLv;
  const ushort_t* Lb = Xlo + (size_t)b*MMv*LLv;
  for(int idx=t; idx<2048; idx+=1024){      // 32 rows x 64 ushort8 chunks
    int mm = idx >> 6, c8 = (idx & 63)*8;
    *(bf16x8*)&Ah[mm*520 + c8] = *(const bf16x8*)&Hb[(size_t)(m0+mm)*LLv + c8];
    *(bf16x8*)&Al[mm*520 + c8] = *(const bf16x8*)&Lb[(size_t)(m0+mm)*LLv + c8];
  }
  __syncthreads();
  const double* Sb = S64 + b*MMv;
  const double* Rb = R64 + b*MMv;
  int nbase = wave*32;                      // 16 waves cover the 512 n-columns
  float corr[16];                           // [cs][mtile][r], static-indexed
  int nnv[2];
  #pragma unroll
  for(int cs=0; cs<2; cs++){
    int nn = nbase + cs*16 + l16;           // B row this lane streams
    nnv[cs] = nn;
    size_t brow = (size_t)nn*LLv + quad*8;  // lane's K-offset folded in
    f32x4 acc0 = {0.f,0.f,0.f,0.f};
    f32x4 acc1 = {0.f,0.f,0.f,0.f};
    if(f32){
      #pragma unroll
      for(int kk=0; kk<16; kk++){           // direct loads, no batch arrays
        int ko = kk*32 + quad*8;
        bf16x8 bh = *(const bf16x8*)&Hb[brow + kk*32];
        bf16x8 bl = *(const bf16x8*)&Lb[brow + kk*32];
        bf16x8 ah0 = *(const bf16x8*)&Ah[l16*520 + ko];
        bf16x8 al0 = *(const bf16x8*)&Al[l16*520 + ko];
        bf16x8 ah1 = *(const bf16x8*)&Ah[(16+l16)*520 + ko];
        bf16x8 al1 = *(const bf16x8*)&Al[(16+l16)*520 + ko];
        acc0 = __builtin_amdgcn_mfma_f32_16x16x32_bf16(ah0, bh, acc0, 0, 0, 0);
        acc0 = __builtin_amdgcn_mfma_f32_16x16x32_bf16(ah0, bl, acc0, 0, 0, 0);
        acc0 = __builtin_amdgcn_mfma_f32_16x16x32_bf16(al0, bh, acc0, 0, 0, 0);
        acc1 = __builtin_amdgcn_mfma_f32_16x16x32_bf16(ah1, bh, acc1, 0, 0, 0);
        acc1 = __builtin_amdgcn_mfma_f32_16x16x32_bf16(ah1, bl, acc1, 0, 0, 0);
        acc1 = __builtin_amdgcn_mfma_f32_16x16x32_bf16(al1, bh, acc1, 0, 0, 0);
      }
    } else {
      #pragma unroll
      for(int g=0; g<4; g++){               // 4 groups x 4 K-steps
        bf16x8 bh[4];
        #pragma unroll
        for(int j=0;j<4;j++) bh[j] = *(const bf16x8*)&Hb[brow + g*128 + j*32];
        #pragma unroll
        for(int j=0;j<4;j++){
          int ko = g*128 + j*32 + quad*8;
          bf16x8 ah0 = *(const bf16x8*)&Ah[l16*520 + ko];
          bf16x8 ah1 = *(const bf16x8*)&Ah[(16+l16)*520 + ko];
          acc0 = __builtin_amdgcn_mfma_f32_16x16x32_bf16(ah0, bh[j], acc0, 0, 0, 0);
          acc1 = __builtin_amdgcn_mfma_f32_16x16x32_bf16(ah1, bh[j], acc1, 0, 0, 0);
        }
      }
    }
    float sn = (float)(Sb[nn]*(1.0/LLv));
    float rn = (float)Rb[nn];
    #pragma unroll
    for(int r=0;r<4;r++){
      int ml0 = quad*4 + r;                 // C/D: row = quad*4 + reg, col = lane&15
      float cov0 = (acc0[r] - (float)Sb[m0+ml0]*sn) * (1.0f/(LLv-1));
      corr[cs*8 + r] = cov0 * (float)Rb[m0+ml0] * rn;
      int ml1 = 16 + ml0;
      float cov1 = (acc1[r] - (float)Sb[m0+ml1]*sn) * (1.0f/(LLv-1));
      corr[cs*8 + 4 + r] = cov1 * (float)Rb[m0+ml1] * rn;
    }
  }
  __syncthreads();                          // all Ah/Al reads complete
  #pragma unroll
  for(int cs=0; cs<2; cs++){
    #pragma unroll
    for(int r=0;r<4;r++){
      int ml0 = quad*4 + r;
      Cs[ml0*516 + nnv[cs]] = corr[cs*8 + r];
      Cs[(16+ml0)*516 + nnv[cs]] = corr[cs*8 + 4 + r];
    }
  }
  __syncthreads();
  // each wave owns 2 rows; selection in-wave only, all-register vals[]
  for(int rr=0; rr<2; rr++){
    int r = wave*2 + rr;
    float vals[8];
    #pragma unroll
    for(int j=0;j<8;j++) vals[j] = Cs[r*516 + lane + 64*j];
    for(int it=0; it<=KNB; it++){
      float bvv = FLT_MAX; int bi = 0x7fffffff;
      #pragma unroll
      for(int j=0;j<8;j++){
        int n = lane + 64*j;
        if(vals[j] < bvv){ bvv = vals[j]; bi = n; }
      }
      // butterfly (min value, tie -> min index) over 64 lanes
      #pragma unroll
      for(int s=32; s; s>>=1){
        float v2 = __shfl_xor(bvv, s);
        int   i2 = __shfl_xor(bi,  s);
        if(v2 < bvv || (v2 == bvv && i2 < bi)){ bvv = v2; bi = i2; }
      }
      int gbi = bi;                          // uniform across the wave
      int bic = min(max(gbi, 0), MMv-1);     // clamp: bad data -> wrong answer, never a fault
      if(it > 0 && lane == 0) nbr[(size_t)(b*MMv + m0 + r)*KNB + it-1] = bic;
      if((gbi & 63) == lane && gbi < MMv){
        int jj = gbi >> 6;                   // static-index clear: stays in VGPRs
        #pragma unroll
        for(int j=0;j<8;j++) if(j == jj) vals[j] = FLT_MAX;
      }
    }
  }
}

// ---- graph build (all data-dependent indices clamped) ----
__global__ __launch_bounds__(256) void zero_k(int* p){
  p[blockIdx.x*256 + threadIdx.x] = 0;
}

__global__ __launch_bounds__(256) void hist_k(const int* nbr, int* cnt){
  int tid = blockIdx.x*256 + threadIdx.x;
  int b = tid >> 13;
  int col = min(max(nbr[tid], 0), MMv-1);
  atomicAdd(&cnt[b*MMv + col], 1);
}

__global__ __launch_bounds__(256) void scan_k(const int* cnt, int* off,
                                              int* cursor, float* dinv){
  __shared__ int part[256];
  int t = threadIdx.x;
  int base = t*64, s = 0;
  for(int i=0;i<64;i++) s += cnt[base+i];
  part[t] = s; __syncthreads();
  for(int st=1; st<256; st<<=1){
    int v = (t >= st) ? part[t-st] : 0;
    __syncthreads();
    part[t] += v; __syncthreads();
  }
  int run = (t > 0) ? part[t-1] : 0;
  for(int i=0;i<64;i++){
    int idx = base+i;
    off[idx] = run; cursor[idx] = run;
    run += cnt[idx];
    dinv[idx] = 1.0f/sqrtf((float)(cnt[idx]+1));   // +1 self loop
  }
  if(t == 255) off[NNODE] = run;
}

__global__ __launch_bounds__(256) void fill_k(const int* nbr, int* cursor, int* esrc){
  int tid = blockIdx.x*256 + threadIdx.x;   // edge: b*8192 + e, e = m*16+k
  int b = tid >> 13;
  int rem = tid & 8191;
  int col = min(max(nbr[tid], 0), MMv-1);
  int dst = b*MMv + col;
  int srcl = rem & 511;                      // src = e mod 512 (faithful tile() quirk)
  int pos = atomicAdd(&cursor[dst], 1);
  pos = min(max(pos, 0), TOTE-1);
  esrc[pos] = b*MMv + srcl;
}

// ---- split-bf16 MFMA GEMM: C = A*Wt^T (+bias)(+relu). BM=64, BN=32. ----
__global__ __launch_bounds__(256) void gemm_k(const float* A,
                                              const ushort_t* Wth, const ushort_t* Wtl,
                                              size_t woffT, int wdi,
                                              const void* bias, int boff, int bdi,
                                              float* C, int Kd, int Dout, int relu,
                                              const int* DF){
  __shared__ __attribute__((aligned(16))) ushort_t Ah[64*72];
  __shared__ __attribute__((aligned(16))) ushort_t Al[64*72];
  __shared__ __attribute__((aligned(16))) ushort_t Wh[32*72];
  __shared__ __attribute__((aligned(16))) ushort_t Wl[32*72];
  int wf32 = DF[wdi];
  int bf32 = DF[bdi];
  int m0 = blockIdx.y*64, n0 = blockIdx.x*32;
  int t = threadIdx.x;
  int wave = t >> 6, lane = t & 63;
  int quad = lane >> 4, l16 = lane & 15;
  f32x4 acc[2];
  #pragma unroll
  for(int nt=0;nt<2;nt++) acc[nt] = (f32x4){0.f,0.f,0.f,0.f};
  for(int kc=0; kc<Kd; kc+=64){
    for(int s=t; s<1024; s+=256){           // A: 64 rows x 16 float4
      int row = s >> 4, c4 = (s & 15)*4;
      float4 av = *(const float4*)&A[(size_t)(m0+row)*Kd + kc + c4];
      ushort_t h0=f2bf(av.x), h1=f2bf(av.y), h2=f2bf(av.z), h3=f2bf(av.w);
      ushort_t g0=f2bf(av.x-bf2f(h0)), g1=f2bf(av.y-bf2f(h1));
      ushort_t g2=f2bf(av.z-bf2f(h2)), g3=f2bf(av.w-bf2f(h3));
      *(ushort4*)&Ah[row*72 + c4] = make_ushort4(h0,h1,h2,h3);
      *(ushort4*)&Al[row*72 + c4] = make_ushort4(g0,g1,g2,g3);
    }
    for(int s=t; s<256; s+=256){            // W^T: 32 rows x 8 ushort8
      int row = s >> 3, c8 = (s & 7)*8;
      size_t g = woffT + (size_t)(n0+row)*Kd + kc + c8;
      *(bf16x8*)&Wh[row*72 + c8] = *(const bf16x8*)&Wth[g];
      if(wf32) *(bf16x8*)&Wl[row*72 + c8] = *(const bf16x8*)&Wtl[g];
    }
    __syncthreads();
    #pragma unroll
    for(int kk=0; kk<64; kk+=32){
      int ko = kk + quad*8;
      bf16x8 ah = *(const bf16x8*)&Ah[(wave*16+l16)*72 + ko];
      bf16x8 al = *(const bf16x8*)&Al[(wave*16+l16)*72 + ko];
      #pragma unroll
      for(int nt=0; nt<2; nt++){
        bf16x8 wh = *(const bf16x8*)&Wh[(nt*16+l16)*72 + ko];
        acc[nt] = __builtin_amdgcn_mfma_f32_16x16x32_bf16(ah, wh, acc[nt], 0, 0, 0);
        acc[nt] = __builtin_amdgcn_mfma_f32_16x16x32_bf16(al, wh, acc[nt], 0, 0, 0);
        if(wf32){
          bf16x8 wl = *(const bf16x8*)&Wl[(nt*16+l16)*72 + ko];
          acc[nt] = __builtin_amdgcn_mfma_f32_16x16x32_bf16(ah, wl, acc[nt], 0, 0, 0);
        }
      }
    }
    __syncthreads();
  }
  #pragma unroll
  for(int nt=0; nt<2; nt++){
    int n = n0 + nt*16 + l16;
    float bv = bias ? ldx(bias, boff + n, bf32) : 0.f;
    #pragma unroll
    for(int r=0; r<2*2; r++){
      float v = acc[nt][r] + bv;              // C/D: row = quad*4+r, col = l16
      if(relu) v = fmaxf(v, 0.f);
      C[(size_t)(m0 + wave*16 + quad*4 + r)*Dout + n] = v;
    }
  }
}

// ---- fused QKV projection, BN=32: grid (12,256).
// n0<128: Q = hF x Wq -> t0[.,128]; else K/V = xg x W(kv) -> kv[.,256]. ----
__global__ __launch_bounds__(256) void qkv_k(const float* hF, const float* xg,
                                             const ushort_t* Wth, const ushort_t* Wtl,
                                             size_t qoff, float* t0, float* kv,
                                             const int* DF){
  __shared__ __attribute__((aligned(16))) ushort_t Ah[64*72];
  __shared__ __attribute__((aligned(16))) ushort_t Al[64*72];
  __shared__ __attribute__((aligned(16))) ushort_t Wh[32*72];
  __shared__ __attribute__((aligned(16))) ushort_t Wl[32*72];
  int m0 = blockIdx.y*64, n0 = blockIdx.x*32;   // n0 in [0,384)
  int wdi = (n0 < 128) ? 6 : ((n0 < 256) ? 7 : 8);
  int wf32 = DF[wdi];
  const float* A = (n0 < 128) ? hF : xg;
  int t = threadIdx.x;
  int wave = t >> 6, lane = t & 63;
  int quad = lane >> 4, l16 = lane & 15;
  f32x4 acc[2];
  #pragma unroll
  for(int nt=0;nt<2;nt++) acc[nt] = (f32x4){0.f,0.f,0.f,0.f};
  for(int kc=0; kc<DDv; kc+=64){
    for(int s=t; s<1024; s+=256){
      int row = s >> 4, c4 = (s & 15)*4;
      float4 av = *(const float4*)&A[(size_t)(m0+row)*DDv + kc + c4];
      ushort_t h0=f2bf(av.x), h1=f2bf(av.y), h2=f2bf(av.z), h3=f2bf(av.w);
      ushort_t g0=f2bf(av.x-bf2f(h0)), g1=f2bf(av.y-bf2f(h1));
      ushort_t g2=f2bf(av.z-bf2f(h2)), g3=f2bf(av.w-bf2f(h3));
      *(ushort4*)&Ah[row*72 + c4] = make_ushort4(h0,h1,h2,h3);
      *(ushort4*)&Al[row*72 + c4] = make_ushort4(g0,g1,g2,g3);
    }
    for(int s=t; s<256; s+=256){
      int row = s >> 3, c8 = (s & 7)*8;
      size_t g = qoff + (size_t)(n0+row)*DDv + kc + c8;
      *(bf16x8*)&Wh[row*72 + c8] = *(const bf16x8*)&Wth[g];
      if(wf32) *(bf16x8*)&Wl[row*72 + c8] = *(const bf16x8*)&Wtl[g];
    }
    __syncthreads();
    #pragma unroll
    for(int kk=0; kk<64; kk+=32){
      int ko = kk + quad*8;
      bf16x8 ah = *(const bf16x8*)&Ah[(wave*16+l16)*72 + ko];
      bf16x8 al = *(const bf16x8*)&Al[(wave*16+l16)*72 + ko];
      #pragma unroll
      for(int nt=0; nt<2; nt++){
        bf16x8 wh = *(const bf16x8*)&Wh[(nt*16+l16)*72 + ko];
        acc[nt] = __builtin_amdgcn_mfma_f32_16x16x32_bf16(ah, wh, acc[nt], 0, 0, 0);
        acc[nt] = __builtin_amdgcn_mfma_f32_16x16x32_bf16(al, wh, acc[nt], 0, 0, 0);
        if(wf32){
          bf16x8 wl = *(const bf16x8*)&Wl[(nt*16+l16)*72 + ko];
          acc[nt] = __builtin_amdgcn_mfma_f32_16x16x32_bf16(ah, wl, acc[nt], 0, 0, 0);
        }
      }
    }
    __syncthreads();
  }
  float* C = (n0 < 128) ? t0 : kv;
  int ldC = (n0 < 128) ? 128 : 256;
  int nb  = (n0 < 128) ? n0 : (n0 - 128);
  #pragma unroll
  for(int nt=0; nt<2; nt++){
    int n = nb + nt*16 + l16;
    #pragma unroll
    for(int r=0; r<4; r++){
      C[(size_t)(m0 + wave*16 + quad*4 + r)*ldC + n] = acc[nt][r];
    }
  }
}

// ---- GCN aggregation: 4x-unrolled gather ----
__global__ __launch_bounds__(256) void agg_k(const float* xw, const int* off,
                                             const int* esrc, const float* dinv,
                                             const void* bias, int bdi, float* out,
                                             const int* DF){
  int f32 = DF[bdi];
  int node = blockIdx.x*4 + (threadIdx.x >> 6);
  int lane = threadIdx.x & 63;
  float dn = dinv[node];
  float2 xv = ((const float2*)(xw + (size_t)node*DDv))[lane];
  float a0 = dn*dn*xv.x;
  float a1 = dn*dn*xv.y;
  int e0 = min(max(off[node], 0), TOTE);
  int e1 = min(max(off[node+1], e0), TOTE);
  int e = e0;
  for(; e + 4 <= e1; e += 4){
    int s0 = min(max(esrc[e+0], 0), NNODE-1);
    int s1 = min(max(esrc[e+1], 0), NNODE-1);
    int s2 = min(max(esrc[e+2], 0), NNODE-1);
    int s3 = min(max(esrc[e+3], 0), NNODE-1);
    float2 v0 = ((const float2*)(xw + (size_t)s0*DDv))[lane];
    float2 v1 = ((const float2*)(xw + (size_t)s1*DDv))[lane];
    float2 v2 = ((const float2*)(xw + (size_t)s2*DDv))[lane];
    float2 v3 = ((const float2*)(xw + (size_t)s3*DDv))[lane];
    float w0 = dinv[s0]*dn, w1 = dinv[s1]*dn, w2 = dinv[s2]*dn, w3 = dinv[s3]*dn;
    a0 = fmaf(w0, v0.x, a0); a1 = fmaf(w0, v0.y, a1);
    a0 = fmaf(w1, v1.x, a0); a1 = fmaf(w1, v1.y, a1);
    a0 = fmaf(w2, v2.x, a0); a1 = fmaf(w2, v2.y, a1);
    a0 = fmaf(w3, v3.x, a0); a1 = fmaf(w3, v3.y, a1);
  }
  for(; e < e1; e++){
    int s = min(max(esrc[e], 0), NNODE-1);
    float w = dinv[s]*dn;
    float2 sv = ((const float2*)(xw + (size_t)s*DDv))[lane];
    a0 = fmaf(w, sv.x, a0);
    a1 = fmaf(w, sv.y, a1);
  }
  a0 += ldx(bias, 2*lane, f32); a1 += ldx(bias, 2*lane+1, f32);
  ((float2*)(out + (size_t)node*DDv))[lane] = make_float2(fmaxf(a0,0.f), fmaxf(a1,0.f));
}

// ---- cross-attention, split-K flash: 1024 threads, exact two-state merge.
// Q prescaled by 0.25*log2(e); exp2f replaces __expf (saves the per-iter
// scale mul + internal log2e mul; softmax invariant to this rescaling). ----
__global__ __launch_bounds__(1024) void attn_k(const float* qg, const float* kv,
                                               float* og){
  __shared__ float Ks[512*16];
  __shared__ float Vs[512*16];
  int bh = blockIdx.x;
  int b = bh >> 3, hh = bh & 7;
  size_t baseq = (size_t)b*MMv*DDv + (size_t)hh*16;
  size_t basekv = (size_t)b*MMv*256 + (size_t)hh*16;
  int t = threadIdx.x;
  for(int idx=t; idx<2048; idx+=1024){       // 512 rows x 4 float4
    int kk = idx >> 2, i4 = (idx & 3)*4;
    ((float4*)Ks)[idx] = *(const float4*)&kv[basekv + (size_t)kk*256 + i4];
    ((float4*)Vs)[idx] = *(const float4*)&kv[basekv + (size_t)kk*256 + 128 + i4];
  }
  __syncthreads();
  int r = t & 511, g = t >> 9;
  const float QS = 0.25f * 1.4426950408889634f;   // 0.25 * log2(e)
  float qr[16];
  #pragma unroll
  for(int i4=0;i4<4;i4++){
    float4 qv = *(const float4*)&qg[baseq + (size_t)r*DDv + i4*4];
    qr[i4*4+0]=qv.x*QS; qr[i4*4+1]=qv.y*QS; qr[i4*4+2]=qv.z*QS; qr[i4*4+3]=qv.w*QS;
  }
  float m = -FLT_MAX, l = 0.f;
  float acc[16] = {};
  int k0 = g*256;
  for(int kk=k0; kk<k0+256; kk++){
    const float* kp = &Ks[kk*16];
    float s = 0.f;
    #pragma unroll
    for(int i=0;i<16;i++) s = fmaf(qr[i], kp[i], s);
    if(s > m){                               // rare after warm-up
      float c = exp2f(m - s);
      l *= c;
      #pragma unroll
      for(int i=0;i<16;i++) acc[i] *= c;
      m = s;
    }
    float p = exp2f(s - m);
    l += p;
    const float* vp = &Vs[kk*16];
    #pragma unroll
    for(int i=0;i<16;i++) acc[i] = fmaf(p, vp[i], acc[i]);
  }
  __syncthreads();                           // K/V consumption complete
  if(g == 1){                                // publish partial state
    #pragma unroll
    for(int i=0;i<16;i++) Ks[r*16 + i] = acc[i];
    Vs[r] = m; Vs[512 + r] = l;
  }
  __syncthreads();
  if(g == 0){                                // exact two-state merge (base-2 domain)
    float m1 = Vs[r], l1 = Vs[512 + r];
    float M = fmaxf(m, m1);
    float c0 = exp2f(m - M), c1 = exp2f(m1 - M);
    float inv = 1.0f/(l*c0 + l1*c1);
    #pragma unroll
    for(int i=0;i<16;i++)
      og[baseq + (size_t)r*DDv + i] = (acc[i]*c0 + Ks[r*16 + i]*c1)*inv;
  }
}

// ---- residual + LayerNorm: wave per row, shuffle-reduced, fp32 ----
__global__ __launch_bounds__(256) void ln_k(const float* h, const float* delta,
                                            const void* g, int gdi, const void* bb, int bdi, int po,
                                            float* dst, const int* DF){
  int gf32 = DF[gdi], bf32 = DF[bdi];
  int row = blockIdx.x*4 + (threadIdx.x >> 6);
  int lane = threadIdx.x & 63;
  const float2* hr = (const float2*)(h + (size_t)row*DDv);
  const float2* dr = (const float2*)(delta + (size_t)row*DDv);
  float2 hv = hr[lane], dv = dr[lane];
  float x0 = hv.x + dv.x, x1 = hv.y + dv.y;
  float mu = wsum(x0 + x1) * (1.0f/DDv);
  float d0 = x0 - mu, d1 = x1 - mu;
  float var = wsum(d0*d0 + d1*d1) * (1.0f/DDv);
  float rs = 1.0f/sqrtf(var + 1e-5f);
  int c0 = lane*2;
  float y0 = d0*rs*ldx(g, po+c0,   gf32) + ldx(bb, po+c0,   bf32);
  float y1 = d1*rs*ldx(g, po+c0+1, gf32) + ldx(bb, po+c0+1, bf32);
  ((float2*)(dst + (size_t)row*DDv))[lane] = make_float2(y0, y1);
}

// ---- enc -> fp32 h ----
__global__ __launch_bounds__(256) void cvt_k(const void* in, float* out, const int* DF){
  int f32 = DF[0];
  int tid = blockIdx.x*256 + threadIdx.x;
  out[tid] = ldx(in, tid, f32);
}

extern "C" void kernel_launch(void* const* d_in, const int* in_sizes, int n_in,
                              void* d_out, int out_size, void* d_ws, size_t ws_size,
                              hipStream_t stream) {
  if(n_in != 18){
    diag_fill_k<<<256, 256, 0, stream>>>((float*)d_out, out_size, 1000.0f);
    return;
  }
  const int expect[18] = {
    BB*MMv*DDv, BB*LLv*MMv, DDv*DDv, DDv, DDv*DDv, DDv,
    NLAY*DDv*DDv, NLAY*DDv*DDv, NLAY*DDv*DDv, NLAY*DDv*DDv,
    NLAY*DDv*DFFv, NLAY*DFFv, NLAY*DFFv*DDv, NLAY*DDv,
    NLAY*DDv, NLAY*DDv, NLAY*DDv, NLAY*DDv
  };
  for(int i=0;i<18;i++){
    if(in_sizes[i] != expect[i]){
      diag_fill_k<<<256, 256, 0, stream>>>((float*)d_out, out_size, 2000.0f + 10.0f*i);
      return;
    }
  }

  const void* enc  = d_in[0];
  const void* xe   = d_in[1];
  const void* c1W  = d_in[2];
  const void* c1b  = d_in[3];
  const void* c2W  = d_in[4];
  const void* c2b  = d_in[5];
  const void* Wq   = d_in[6];
  const void* Wk   = d_in[7];
  const void* Wv   = d_in[8];
  const void* Wo   = d_in[9];
  const void* W1   = d_in[10];
  const void* b1   = d_in[11];
  const void* W2   = d_in[12];
  const void* b2   = d_in[13];
  const void* ln1g = d_in[14];
  const void* ln1b = d_in[15];
  const void* ln2g = d_in[16];
  const void* ln2b = d_in[17];

  char* ws = (char*)d_ws;
  size_t o = 0;
  auto alloc = [&](size_t bytes){ size_t r = o; o = (o + bytes + 255) & ~(size_t)255; return r; };
  double* S64  = (double*)(ws + alloc((size_t)NNODE*8));
  double* R64  = (double*)(ws + alloc((size_t)NNODE*8));
  float* dinv  = (float*)(ws + alloc((size_t)NNODE*4));
  int*   cnt   = (int*)  (ws + alloc((size_t)NNODE*4));
  int*   cursor= (int*)  (ws + alloc((size_t)NNODE*4));
  int*   off   = (int*)  (ws + alloc((size_t)(NNODE+1)*4));
  int*   nbr   = (int*)  (ws + alloc((size_t)TOTE*4));
  int*   esrc  = (int*)  (ws + alloc((size_t)TOTE*4));
  int*   DF    = (int*)  (ws + alloc(256));
  ushort_t* Wth = (ushort_t*)(ws + alloc((size_t)WTOT*2));
  ushort_t* Wtl = (ushort_t*)(ws + alloc((size_t)WTOT*2));
  const size_t ACTF = (size_t)NNODE*DDv*4;   // fp32 activation: 8.39 MB
  float* hF = (float*)(ws + alloc(ACTF));
  float* xg = (float*)(ws + alloc(ACTF));
  float* t0 = (float*)(ws + alloc(ACTF));
  float* t1 = (float*)(ws + alloc(ACTF));
  float* t2 = (float*)(ws + alloc(ACTF));    // t1+t2 contiguous: kv[NNODE][256] / ffn hidden
  float* t3 = (float*)(ws + alloc(ACTF));
  float* kv = t1;                             // 16.78 MB span
  float* fb = t1;                             // ffn hidden; kv dead when ffn runs
  // Xhi/Xlo (graph phase only) overlay hF..t1 — consumed by corrsel before cvt_k writes hF
  ushort_t* Xhi = (ushort_t*)hF;
  ushort_t* Xlo = Xhi + (size_t)BB*MMv*LLv;   // 16.78 MB each
  if(ws_size < o){
    diag_fill_k<<<256, 256, 0, stream>>>((float*)d_out, out_size, 3000.0f);
    return;
  }

  // ---- per-input dtype detection + weight transpose/split prep ----
  P18 pack;
  for(int i=0;i<18;i++){ pack.p[i] = (const ushort_t*)d_in[i]; pack.n[i] = in_sizes[i]; }
  ddet_k<<<18, 256, 0, stream>>>(pack, DF);
  prep_k<<<dim3(8,8,14), dim3(32,8), 0, stream>>>(c1W, c2W, Wq, Wk, Wv, Wo, W1, W2,
                                                  Wth, Wtl, DF);

  // --- graph construction (split-bf16 MFMA corr + hi/lo stats + selection) ---
  split_k<<<dim3(16,16,BB), dim3(32,8), 0, stream>>>(xe, Xhi, Xlo, DF);
  stats2_k<<<NNODE/4, 256, 0, stream>>>(Xhi, Xlo, S64, R64);
  corrsel_k<<<dim3(16, BB), 1024, 0, stream>>>(Xhi, Xlo, S64, R64, nbr, DF);
  zero_k<<<NNODE/256, 256, 0, stream>>>(cnt);
  hist_k<<<TOTE/256, 256, 0, stream>>>(nbr, cnt);
  scan_k<<<1, 256, 0, stream>>>(cnt, off, cursor, dinv);
  fill_k<<<TOTE/256, 256, 0, stream>>>(nbr, cursor, esrc);

  // --- GCN (2 layers, fp32 activations, MFMA gemms) ---
  cvt_k<<<NNODE*DDv/256, 256, 0, stream>>>(enc, hF, DF);
  gemm_k<<<dim3(4,256), 256, 0, stream>>>(hF, Wth, Wtl, 0, 2, nullptr, 0, 3, t0, DDv, DDv, 0, DF);
  agg_k<<<NNODE/4, 256, 0, stream>>>(t0, off, esrc, dinv, c1b, 3, t1, DF);
  gemm_k<<<dim3(4,256), 256, 0, stream>>>(t1, Wth, Wtl, 16384, 4, nullptr, 0, 5, t0, DDv, DDv, 0, DF);
  agg_k<<<NNODE/4, 256, 0, stream>>>(t0, off, esrc, dinv, c2b, 5, xg, DF);

  // --- transformer (2 layers; query stream = hF, kv = xg) ---
  for(int l=0; l<NLAY; l++){
    qkv_k<<<dim3(12,256), 256, 0, stream>>>(hF, xg, Wth, Wtl,
                                            32768 + (size_t)l*49152, t0, kv, DF);
    attn_k<<<BB*HHv, 1024, 0, stream>>>(t0, kv, t3);
    gemm_k<<<dim3(4,256), 256, 0, stream>>>(t3, Wth, Wtl, 131072 + (size_t)l*16384, 9, nullptr, 0, 9, t0, DDv, DDv, 0, DF);
    ln_k<<<NNODE/4, 256, 0, stream>>>(hF, t0, ln1g, 14, ln1b, 15, l*DDv, hF, DF);
    gemm_k<<<dim3(8,256), 256, 0, stream>>>(hF, Wth, Wtl, 163840 + (size_t)l*32768, 10, b1, l*DFFv, 11, fb, DDv, DFFv, 1, DF);
    gemm_k<<<dim3(4,256), 256, 0, stream>>>(fb, Wth, Wtl, 229376 + (size_t)l*32768, 12, b2, l*DDv, 13, t0, DFFv, DDv, 0, DF);
    float* dst = (l == NLAY-1) ? (float*)d_out : hF;
    ln_k<<<NNODE/4, 256, 0, stream>>>(hF, t0, ln2g, 16, ln2b, 17, l*DDv, dst, DF);
  }
}

// Round 17
// 707.847 us; speedup vs baseline: 1.0452x; 1.0133x over previous
//
#include <hip/hip_runtime.h>
#include <float.h>

#define BB 32
#define MMv 512
#define LLv 512
#define DDv 128
#define HHv 8
#define DFFv 256
#define KNB 16
#define NLAY 2
#define NNODE (BB*MMv)       // 16384
#define TOTE  (NNODE*KNB)    // 262144 edges
#define WTOT  294912         // total transposed weight elements

typedef unsigned short ushort_t;
typedef unsigned int u32;
typedef __attribute__((ext_vector_type(8))) short bf16x8;
typedef __attribute__((ext_vector_type(4))) float f32x4;

__device__ __forceinline__ float bf2f(ushort_t u){
  union { u32 i; float f; } x; x.i = ((u32)u) << 16; return x.f;
}
__device__ __forceinline__ ushort_t f2bf(float f){
  union { u32 i; float f; } x; x.f = f;
  u32 r = x.i + 0x7FFFu + ((x.i >> 16) & 1u);   // RNE
  return (ushort_t)(r >> 16);
}
__device__ __forceinline__ float ldx(const void* p, size_t i, int f32){
  return f32 ? ((const float*)p)[i] : bf2f(((const ushort_t*)p)[i]);
}
__device__ __forceinline__ float wsum(float v){
  #pragma unroll
  for(int s=32;s;s>>=1) v += __shfl_xor(v,s);
  return v;
}

// ---- diagnostics (fp32 output) ----
__global__ __launch_bounds__(256) void diag_fill_k(float* out, int n, float val){
  for(int i = blockIdx.x*256 + threadIdx.x; i < n; i += gridDim.x*256) out[i] = val;
}

// ---- per-input dtype detection (one block per input) ----
struct P18 { const ushort_t* p[18]; int n[18]; };
__global__ __launch_bounds__(256) void ddet_k(P18 a, int* DF){
  int i = blockIdx.x;
  const ushort_t* q = a.p[i];
  int P = min(a.n[i], 4096);
  int t = threadIdx.x;
  int r1 = 0, evenNZ = 0, oddNZ = 0;
  for(int j=t; j<P; j+=256){
    ushort_t v = q[j];
    if(((v >> 7) & 0xFF) >= 0xC0) r1 = 1;   // impossible exponent for real bf16 data
    if(v){ if(j & 1) oddNZ = 1; else evenNZ = 1; }
  }
  __shared__ int sh[3];
  if(t==0){ sh[0]=0; sh[1]=0; sh[2]=0; }
  __syncthreads();
  if(r1) atomicOr(&sh[0],1);
  if(evenNZ) atomicOr(&sh[1],1);
  if(oddNZ) atomicOr(&sh[2],1);
  __syncthreads();
  if(t==0) DF[i] = sh[0] | ((sh[1]==0) & (sh[2]!=0));
}

// ---- weight prep: transpose + hi/lo split of all 14 weight slices, ONCE. ----
__global__ __launch_bounds__(256) void prep_k(const void* c1W, const void* c2W,
    const void* Wq, const void* Wk, const void* Wv, const void* Wo,
    const void* W1, const void* W2, ushort_t* Wth, ushort_t* Wtl, const int* DF){
  __shared__ ushort_t th[32][33];
  __shared__ ushort_t tl[32][33];
  int job = blockIdx.z;
  const void* src; int dfi; size_t soff, doff; int K, N;
  switch(job){
    case 0:  src=c1W; dfi=2;  soff=0; K=128; N=128; doff=0; break;
    case 1:  src=c2W; dfi=4;  soff=0; K=128; N=128; doff=16384; break;
    case 2: case 3:   // Wq layer 0,1 -> QKV block rows 0..127
      src=Wq; dfi=6; soff=(size_t)(job-2)*16384; K=128; N=128;
      doff=32768 + (size_t)(job-2)*49152; break;
    case 4: case 5:   // Wk -> QKV block rows 128..255
      src=Wk; dfi=7; soff=(size_t)(job-4)*16384; K=128; N=128;
      doff=32768 + (size_t)(job-4)*49152 + 16384; break;
    case 6: case 7:   // Wv -> QKV block rows 256..383
      src=Wv; dfi=8; soff=(size_t)(job-6)*16384; K=128; N=128;
      doff=32768 + (size_t)(job-6)*49152 + 32768; break;
    case 8: case 9:
      src=Wo; dfi=9; soff=(size_t)(job-8)*16384; K=128; N=128;
      doff=131072 + (size_t)(job-8)*16384; break;
    case 10: case 11:
      src=W1; dfi=10; soff=(size_t)(job-10)*32768; K=128; N=256;
      doff=163840 + (size_t)(job-10)*32768; break;
    default:
      src=W2; dfi=12; soff=(size_t)(job-12)*32768; K=256; N=128;
      doff=229376 + (size_t)(job-12)*32768; break;
  }
  int n0 = blockIdx.x*32, k0 = blockIdx.y*32;
  if(n0 >= N || k0 >= K) return;
  int f32 = DF[dfi];
  int tx = threadIdx.x, ty = threadIdx.y;   // 32 x 8
  #pragma unroll
  for(int i=0;i<4;i++){
    int k = k0+ty+8*i, n = n0+tx;
    float x = ldx(src, soff + (size_t)k*N + n, f32);
    ushort_t hi = f2bf(x);
    ushort_t lo = f2bf(x - bf2f(hi));
    th[ty+8*i][tx] = hi; tl[ty+8*i][tx] = lo;
  }
  __syncthreads();
  #pragma unroll
  for(int i=0;i<4;i++){
    int n = n0+ty+8*i, k = k0+tx;
    size_t d = doff + (size_t)n*K + k;
    Wth[d] = th[tx][ty+8*i];
    Wtl[d] = tl[tx][ty+8*i];
  }
}

// ---- split-transpose: x_enc[B,L,M] -> Xhi/Xlo[B,M,L] (x ~= hi+lo, ~2^-17 rel exact) ----
__global__ __launch_bounds__(256) void split_k(const void* xe, ushort_t* Xhi,
                                               ushort_t* Xlo, const int* DF){
  __shared__ ushort_t th[32][33];
  __shared__ ushort_t tl[32][33];
  int f32 = DF[1];
  int b = blockIdx.z;
  int m0 = blockIdx.x*32, l0 = blockIdx.y*32;
  int tx = threadIdx.x, ty = threadIdx.y;   // 32 x 8
  #pragma unroll
  for(int i=0;i<4;i++){
    int l = l0+ty+8*i, m = m0+tx;
    float x = ldx(xe, (size_t)b*LLv*MMv + (size_t)l*MMv + m, f32);
    ushort_t hi = f2bf(x);
    ushort_t lo = f2bf(x - bf2f(hi));
    th[ty+8*i][tx] = hi; tl[ty+8*i][tx] = lo;
  }
  __syncthreads();
  #pragma unroll
  for(int i=0;i<4;i++){
    size_t d = (size_t)b*MMv*LLv + (size_t)(m0+ty+8*i)*LLv + l0+tx;
    Xhi[d] = th[tx][ty+8*i];
    Xlo[d] = tl[tx][ty+8*i];
  }
}

// ---- per-(b,m) sum + rstd from transposed hi/lo rows: wave per row, coalesced ----
__global__ __launch_bounds__(256) void stats2_k(const ushort_t* Xhi, const ushort_t* Xlo,
                                                double* S64, double* R64){
  int row = blockIdx.x*4 + (threadIdx.x >> 6);
  int lane = threadIdx.x & 63;
  const ushort_t* Hr = Xhi + (size_t)row*LLv + lane*8;
  const ushort_t* Lr = Xlo + (size_t)row*LLv + lane*8;
  float s = 0.f, ss = 0.f;
  #pragma unroll
  for(int j=0;j<8;j++){
    float x = bf2f(Hr[j]) + bf2f(Lr[j]);
    s += x; ss = fmaf(x, x, ss);
  }
  s = wsum(s); ss = wsum(ss);
  if(lane == 0){
    S64[row] = (double)s;
    float cov = (ss - s*s*(1.0f/LLv)) * (1.0f/(LLv-1));
    float sd = (cov > 0.f) ? sqrtf(cov) : 0.f;
    R64[row] = (sd > 0.f) ? (double)(1.0f/sd) : 1.0;
  }
}

// ---- MFMA corr strip (split-bf16) + top-(K+1)-smallest selection.
// ROUND-13 OPTIMUM (empirically bracketed): strip=32, 1024 threads, LDS
// overlay (66.6 KB -> 2 blocks/CU, ~77% occ), direct B loads, fan-out 6.
// The (1024,8) VGPR cap induces ~110B/thread scratch spill — measured
// FASTER (123us) than spill-free fan-out-3 (149us) or no-overlay (135us). ----
__global__ __launch_bounds__(1024, 8) void corrsel_k(const ushort_t* Xhi, const ushort_t* Xlo,
                                                     const double* S64, const double* R64,
                                                     int* nbr, const int* DF){
  __shared__ __attribute__((aligned(16))) char smem[66560];
  ushort_t* Ah = (ushort_t*)smem;            // 32*520 bf16
  ushort_t* Al = Ah + 32*520;                // 32*520 bf16
  float*    Cs = (float*)smem;               // 32*516 f32 (overlay, post-compute)
  int f32 = DF[1];
  // bijective swizzle: all 16 strips of a batch share lin%8 (same XCD)
  int lin = blockIdx.y*16 + blockIdx.x;     // 0..511
  int xcd = lin & 7, slot = lin >> 3;       // slot 0..63
  int b = xcd + 8*(slot >> 4);              // b 0..31
  int strip = slot & 15;                    // 16 strips of 32 rows
  int m0 = strip*32;
  int t = threadIdx.x;
  int wave = t >> 6, lane = t & 63;         // 16 waves
  int quad = lane >> 4, l16 = lane & 15;
  const ushort_t* Hb = Xhi + (size_t)b*MMv*LLv;
  const ushort_t* Lb = Xlo + (size_t)b*MMv*LLv;
  for(int idx=t; idx<2048; idx+=1024){      // 32 rows x 64 ushort8 chunks
    int mm = idx >> 6, c8 = (idx & 63)*8;
    *(bf16x8*)&Ah[mm*520 + c8] = *(const bf16x8*)&Hb[(size_t)(m0+mm)*LLv + c8];
    *(bf16x8*)&Al[mm*520 + c8] = *(const bf16x8*)&Lb[(size_t)(m0+mm)*LLv + c8];
  }
  __syncthreads();
  const double* Sb = S64 + b*MMv;
  const double* Rb = R64 + b*MMv;
  int nbase = wave*32;                      // 16 waves cover the 512 n-columns
  float corr[16];                           // [cs][mtile][r], static-indexed
  int nnv[2];
  #pragma unroll
  for(int cs=0; cs<2; cs++){
    int nn = nbase + cs*16 + l16;           // B row this lane streams
    nnv[cs] = nn;
    size_t brow = (size_t)nn*LLv + quad*8;  // lane's K-offset folded in
    f32x4 acc0 = {0.f,0.f,0.f,0.f};
    f32x4 acc1 = {0.f,0.f,0.f,0.f};
    if(f32){
      #pragma unroll
      for(int kk=0; kk<16; kk++){           // direct loads, no batch arrays
        int ko = kk*32 + quad*8;
        bf16x8 bh = *(const bf16x8*)&Hb[brow + kk*32];
        bf16x8 bl = *(const bf16x8*)&Lb[brow + kk*32];
        bf16x8 ah0 = *(const bf16x8*)&Ah[l16*520 + ko];
        bf16x8 al0 = *(const bf16x8*)&Al[l16*520 + ko];
        bf16x8 ah1 = *(const bf16x8*)&Ah[(16+l16)*520 + ko];
        bf16x8 al1 = *(const bf16x8*)&Al[(16+l16)*520 + ko];
        acc0 = __builtin_amdgcn_mfma_f32_16x16x32_bf16(ah0, bh, acc0, 0, 0, 0);
        acc0 = __builtin_amdgcn_mfma_f32_16x16x32_bf16(ah0, bl, acc0, 0, 0, 0);
        acc0 = __builtin_amdgcn_mfma_f32_16x16x32_bf16(al0, bh, acc0, 0, 0, 0);
        acc1 = __builtin_amdgcn_mfma_f32_16x16x32_bf16(ah1, bh, acc1, 0, 0, 0);
        acc1 = __builtin_amdgcn_mfma_f32_16x16x32_bf16(ah1, bl, acc1, 0, 0, 0);
        acc1 = __builtin_amdgcn_mfma_f32_16x16x32_bf16(al1, bh, acc1, 0, 0, 0);
      }
    } else {
      #pragma unroll
      for(int g=0; g<4; g++){               // 4 groups x 4 K-steps
        bf16x8 bh[4];
        #pragma unroll
        for(int j=0;j<4;j++) bh[j] = *(const bf16x8*)&Hb[brow + g*128 + j*32];
        #pragma unroll
        for(int j=0;j<4;j++){
          int ko = g*128 + j*32 + quad*8;
          bf16x8 ah0 = *(const bf16x8*)&Ah[l16*520 + ko];
          bf16x8 ah1 = *(const bf16x8*)&Ah[(16+l16)*520 + ko];
          acc0 = __builtin_amdgcn_mfma_f32_16x16x32_bf16(ah0, bh[j], acc0, 0, 0, 0);
          acc1 = __builtin_amdgcn_mfma_f32_16x16x32_bf16(ah1, bh[j], acc1, 0, 0, 0);
        }
      }
    }
    float sn = (float)(Sb[nn]*(1.0/LLv));
    float rn = (float)Rb[nn];
    #pragma unroll
    for(int r=0;r<4;r++){
      int ml0 = quad*4 + r;                 // C/D: row = quad*4 + reg, col = lane&15
      float cov0 = (acc0[r] - (float)Sb[m0+ml0]*sn) * (1.0f/(LLv-1));
      corr[cs*8 + r] = cov0 * (float)Rb[m0+ml0] * rn;
      int ml1 = 16 + ml0;
      float cov1 = (acc1[r] - (float)Sb[m0+ml1]*sn) * (1.0f/(LLv-1));
      corr[cs*8 + 4 + r] = cov1 * (float)Rb[m0+ml1] * rn;
    }
  }
  __syncthreads();                          // all Ah/Al reads complete
  #pragma unroll
  for(int cs=0; cs<2; cs++){
    #pragma unroll
    for(int r=0;r<4;r++){
      int ml0 = quad*4 + r;
      Cs[ml0*516 + nnv[cs]] = corr[cs*8 + r];
      Cs[(16+ml0)*516 + nnv[cs]] = corr[cs*8 + 4 + r];
    }
  }
  __syncthreads();
  // each wave owns 2 rows; selection in-wave only, all-register vals[]
  for(int rr=0; rr<2; rr++){
    int r = wave*2 + rr;
    float vals[8];
    #pragma unroll
    for(int j=0;j<8;j++) vals[j] = Cs[r*516 + lane + 64*j];
    for(int it=0; it<=KNB; it++){
      float bvv = FLT_MAX; int bi = 0x7fffffff;
      #pragma unroll
      for(int j=0;j<8;j++){
        int n = lane + 64*j;
        if(vals[j] < bvv){ bvv = vals[j]; bi = n; }
      }
      // butterfly (min value, tie -> min index) over 64 lanes
      #pragma unroll
      for(int s=32; s; s>>=1){
        float v2 = __shfl_xor(bvv, s);
        int   i2 = __shfl_xor(bi,  s);
        if(v2 < bvv || (v2 == bvv && i2 < bi)){ bvv = v2; bi = i2; }
      }
      int gbi = bi;                          // uniform across the wave
      int bic = min(max(gbi, 0), MMv-1);     // clamp: bad data -> wrong answer, never a fault
      if(it > 0 && lane == 0) nbr[(size_t)(b*MMv + m0 + r)*KNB + it-1] = bic;
      if((gbi & 63) == lane && gbi < MMv){
        int jj = gbi >> 6;                   // static-index clear: stays in VGPRs
        #pragma unroll
        for(int j=0;j<8;j++) if(j == jj) vals[j] = FLT_MAX;
      }
    }
  }
}

// ---- graph build (all data-dependent indices clamped) ----
__global__ __launch_bounds__(256) void hist_k(const int* nbr, int* cnt){
  int tid = blockIdx.x*256 + threadIdx.x;
  int b = tid >> 13;
  int col = min(max(nbr[tid], 0), MMv-1);
  atomicAdd(&cnt[b*MMv + col], 1);
}

__global__ __launch_bounds__(256) void scan_k(const int* cnt, int* off,
                                              int* cursor, float* dinv){
  __shared__ int part[256];
  int t = threadIdx.x;
  int base = t*64, s = 0;
  for(int i=0;i<64;i++) s += cnt[base+i];
  part[t] = s; __syncthreads();
  for(int st=1; st<256; st<<=1){
    int v = (t >= st) ? part[t-st] : 0;
    __syncthreads();
    part[t] += v; __syncthreads();
  }
  int run = (t > 0) ? part[t-1] : 0;
  for(int i=0;i<64;i++){
    int idx = base+i;
    off[idx] = run; cursor[idx] = run;
    run += cnt[idx];
    dinv[idx] = 1.0f/sqrtf((float)(cnt[idx]+1));   // +1 self loop
  }
  if(t == 255) off[NNODE] = run;
}

__global__ __launch_bounds__(256) void fill_k(const int* nbr, int* cursor, int* esrc){
  int tid = blockIdx.x*256 + threadIdx.x;   // edge: b*8192 + e, e = m*16+k
  int b = tid >> 13;
  int rem = tid & 8191;
  int col = min(max(nbr[tid], 0), MMv-1);
  int dst = b*MMv + col;
  int srcl = rem & 511;                      // src = e mod 512 (faithful tile() quirk)
  int pos = atomicAdd(&cursor[dst], 1);
  pos = min(max(pos, 0), TOTE-1);
  esrc[pos] = b*MMv + srcl;
}

// ---- split-bf16 MFMA GEMM: C = A*Wt^T (+bias)(+relu). BM=64, BN=32. ----
__global__ __launch_bounds__(256) void gemm_k(const float* A,
                                              const ushort_t* Wth, const ushort_t* Wtl,
                                              size_t woffT, int wdi,
                                              const void* bias, int boff, int bdi,
                                              float* C, int Kd, int Dout, int relu,
                                              const int* DF){
  __shared__ __attribute__((aligned(16))) ushort_t Ah[64*72];
  __shared__ __attribute__((aligned(16))) ushort_t Al[64*72];
  __shared__ __attribute__((aligned(16))) ushort_t Wh[32*72];
  __shared__ __attribute__((aligned(16))) ushort_t Wl[32*72];
  int wf32 = DF[wdi];
  int bf32 = DF[bdi];
  int m0 = blockIdx.y*64, n0 = blockIdx.x*32;
  int t = threadIdx.x;
  int wave = t >> 6, lane = t & 63;
  int quad = lane >> 4, l16 = lane & 15;
  f32x4 acc[2];
  #pragma unroll
  for(int nt=0;nt<2;nt++) acc[nt] = (f32x4){0.f,0.f,0.f,0.f};
  for(int kc=0; kc<Kd; kc+=64){
    for(int s=t; s<1024; s+=256){           // A: 64 rows x 16 float4
      int row = s >> 4, c4 = (s & 15)*4;
      float4 av = *(const float4*)&A[(size_t)(m0+row)*Kd + kc + c4];
      ushort_t h0=f2bf(av.x), h1=f2bf(av.y), h2=f2bf(av.z), h3=f2bf(av.w);
      ushort_t g0=f2bf(av.x-bf2f(h0)), g1=f2bf(av.y-bf2f(h1));
      ushort_t g2=f2bf(av.z-bf2f(h2)), g3=f2bf(av.w-bf2f(h3));
      *(ushort4*)&Ah[row*72 + c4] = make_ushort4(h0,h1,h2,h3);
      *(ushort4*)&Al[row*72 + c4] = make_ushort4(g0,g1,g2,g3);
    }
    for(int s=t; s<256; s+=256){            // W^T: 32 rows x 8 ushort8
      int row = s >> 3, c8 = (s & 7)*8;
      size_t g = woffT + (size_t)(n0+row)*Kd + kc + c8;
      *(bf16x8*)&Wh[row*72 + c8] = *(const bf16x8*)&Wth[g];
      if(wf32) *(bf16x8*)&Wl[row*72 + c8] = *(const bf16x8*)&Wtl[g];
    }
    __syncthreads();
    #pragma unroll
    for(int kk=0; kk<64; kk+=32){
      int ko = kk + quad*8;
      bf16x8 ah = *(const bf16x8*)&Ah[(wave*16+l16)*72 + ko];
      bf16x8 al = *(const bf16x8*)&Al[(wave*16+l16)*72 + ko];
      #pragma unroll
      for(int nt=0; nt<2; nt++){
        bf16x8 wh = *(const bf16x8*)&Wh[(nt*16+l16)*72 + ko];
        acc[nt] = __builtin_amdgcn_mfma_f32_16x16x32_bf16(ah, wh, acc[nt], 0, 0, 0);
        acc[nt] = __builtin_amdgcn_mfma_f32_16x16x32_bf16(al, wh, acc[nt], 0, 0, 0);
        if(wf32){
          bf16x8 wl = *(const bf16x8*)&Wl[(nt*16+l16)*72 + ko];
          acc[nt] = __builtin_amdgcn_mfma_f32_16x16x32_bf16(ah, wl, acc[nt], 0, 0, 0);
        }
      }
    }
    __syncthreads();
  }
  #pragma unroll
  for(int nt=0; nt<2; nt++){
    int n = n0 + nt*16 + l16;
    float bv = bias ? ldx(bias, boff + n, bf32) : 0.f;
    #pragma unroll
    for(int r=0; r<2*2; r++){
      float v = acc[nt][r] + bv;              // C/D: row = quad*4+r, col = l16
      if(relu) v = fmaxf(v, 0.f);
      C[(size_t)(m0 + wave*16 + quad*4 + r)*Dout + n] = v;
    }
  }
}

// ---- fused QKV projection, BN=32: grid (12,256).
// n0<128: Q = hF x Wq -> t0[.,128]; else K/V = xg x W(kv) -> kv[.,256]. ----
__global__ __launch_bounds__(256) void qkv_k(const float* hF, const float* xg,
                                             const ushort_t* Wth, const ushort_t* Wtl,
                                             size_t qoff, float* t0, float* kv,
                                             const int* DF){
  __shared__ __attribute__((aligned(16))) ushort_t Ah[64*72];
  __shared__ __attribute__((aligned(16))) ushort_t Al[64*72];
  __shared__ __attribute__((aligned(16))) ushort_t Wh[32*72];
  __shared__ __attribute__((aligned(16))) ushort_t Wl[32*72];
  int m0 = blockIdx.y*64, n0 = blockIdx.x*32;   // n0 in [0,384)
  int wdi = (n0 < 128) ? 6 : ((n0 < 256) ? 7 : 8);
  int wf32 = DF[wdi];
  const float* A = (n0 < 128) ? hF : xg;
  int t = threadIdx.x;
  int wave = t >> 6, lane = t & 63;
  int quad = lane >> 4, l16 = lane & 15;
  f32x4 acc[2];
  #pragma unroll
  for(int nt=0;nt<2;nt++) acc[nt] = (f32x4){0.f,0.f,0.f,0.f};
  for(int kc=0; kc<DDv; kc+=64){
    for(int s=t; s<1024; s+=256){
      int row = s >> 4, c4 = (s & 15)*4;
      float4 av = *(const float4*)&A[(size_t)(m0+row)*DDv + kc + c4];
      ushort_t h0=f2bf(av.x), h1=f2bf(av.y), h2=f2bf(av.z), h3=f2bf(av.w);
      ushort_t g0=f2bf(av.x-bf2f(h0)), g1=f2bf(av.y-bf2f(h1));
      ushort_t g2=f2bf(av.z-bf2f(h2)), g3=f2bf(av.w-bf2f(h3));
      *(ushort4*)&Ah[row*72 + c4] = make_ushort4(h0,h1,h2,h3);
      *(ushort4*)&Al[row*72 + c4] = make_ushort4(g0,g1,g2,g3);
    }
    for(int s=t; s<256; s+=256){
      int row = s >> 3, c8 = (s & 7)*8;
      size_t g = qoff + (size_t)(n0+row)*DDv + kc + c8;
      *(bf16x8*)&Wh[row*72 + c8] = *(const bf16x8*)&Wth[g];
      if(wf32) *(bf16x8*)&Wl[row*72 + c8] = *(const bf16x8*)&Wtl[g];
    }
    __syncthreads();
    #pragma unroll
    for(int kk=0; kk<64; kk+=32){
      int ko = kk + quad*8;
      bf16x8 ah = *(const bf16x8*)&Ah[(wave*16+l16)*72 + ko];
      bf16x8 al = *(const bf16x8*)&Al[(wave*16+l16)*72 + ko];
      #pragma unroll
      for(int nt=0; nt<2; nt++){
        bf16x8 wh = *(const bf16x8*)&Wh[(nt*16+l16)*72 + ko];
        acc[nt] = __builtin_amdgcn_mfma_f32_16x16x32_bf16(ah, wh, acc[nt], 0, 0, 0);
        acc[nt] = __builtin_amdgcn_mfma_f32_16x16x32_bf16(al, wh, acc[nt], 0, 0, 0);
        if(wf32){
          bf16x8 wl = *(const bf16x8*)&Wl[(nt*16+l16)*72 + ko];
          acc[nt] = __builtin_amdgcn_mfma_f32_16x16x32_bf16(ah, wl, acc[nt], 0, 0, 0);
        }
      }
    }
    __syncthreads();
  }
  float* C = (n0 < 128) ? t0 : kv;
  int ldC = (n0 < 128) ? 128 : 256;
  int nb  = (n0 < 128) ? n0 : (n0 - 128);
  #pragma unroll
  for(int nt=0; nt<2; nt++){
    int n = nb + nt*16 + l16;
    #pragma unroll
    for(int r=0; r<4; r++){
      C[(size_t)(m0 + wave*16 + quad*4 + r)*ldC + n] = acc[nt][r];
    }
  }
}

// ---- GCN aggregation: 4x-unrolled gather ----
__global__ __launch_bounds__(256) void agg_k(const float* xw, const int* off,
                                             const int* esrc, const float* dinv,
                                             const void* bias, int bdi, float* out,
                                             const int* DF){
  int f32 = DF[bdi];
  int node = blockIdx.x*4 + (threadIdx.x >> 6);
  int lane = threadIdx.x & 63;
  float dn = dinv[node];
  float2 xv = ((const float2*)(xw + (size_t)node*DDv))[lane];
  float a0 = dn*dn*xv.x;
  float a1 = dn*dn*xv.y;
  int e0 = min(max(off[node], 0), TOTE);
  int e1 = min(max(off[node+1], e0), TOTE);
  int e = e0;
  for(; e + 4 <= e1; e += 4){
    int s0 = min(max(esrc[e+0], 0), NNODE-1);
    int s1 = min(max(esrc[e+1], 0), NNODE-1);
    int s2 = min(max(esrc[e+2], 0), NNODE-1);
    int s3 = min(max(esrc[e+3], 0), NNODE-1);
    float2 v0 = ((const float2*)(xw + (size_t)s0*DDv))[lane];
    float2 v1 = ((const float2*)(xw + (size_t)s1*DDv))[lane];
    float2 v2 = ((const float2*)(xw + (size_t)s2*DDv))[lane];
    float2 v3 = ((const float2*)(xw + (size_t)s3*DDv))[lane];
    float w0 = dinv[s0]*dn, w1 = dinv[s1]*dn, w2 = dinv[s2]*dn, w3 = dinv[s3]*dn;
    a0 = fmaf(w0, v0.x, a0); a1 = fmaf(w0, v0.y, a1);
    a0 = fmaf(w1, v1.x, a0); a1 = fmaf(w1, v1.y, a1);
    a0 = fmaf(w2, v2.x, a0); a1 = fmaf(w2, v2.y, a1);
    a0 = fmaf(w3, v3.x, a0); a1 = fmaf(w3, v3.y, a1);
  }
  for(; e < e1; e++){
    int s = min(max(esrc[e], 0), NNODE-1);
    float w = dinv[s]*dn;
    float2 sv = ((const float2*)(xw + (size_t)s*DDv))[lane];
    a0 = fmaf(w, sv.x, a0);
    a1 = fmaf(w, sv.y, a1);
  }
  a0 += ldx(bias, 2*lane, f32); a1 += ldx(bias, 2*lane+1, f32);
  ((float2*)(out + (size_t)node*DDv))[lane] = make_float2(fmaxf(a0,0.f), fmaxf(a1,0.f));
}

// ---- cross-attention, split-K flash: 1024 threads, exact two-state merge.
// (round-13 best-measured form: __expf, in-loop 0.25 scale) ----
__global__ __launch_bounds__(1024) void attn_k(const float* qg, const float* kv,
                                               float* og){
  __shared__ float Ks[512*16];
  __shared__ float Vs[512*16];
  int bh = blockIdx.x;
  int b = bh >> 3, hh = bh & 7;
  size_t baseq = (size_t)b*MMv*DDv + (size_t)hh*16;
  size_t basekv = (size_t)b*MMv*256 + (size_t)hh*16;
  int t = threadIdx.x;
  for(int idx=t; idx<2048; idx+=1024){       // 512 rows x 4 float4
    int kk = idx >> 2, i4 = (idx & 3)*4;
    ((float4*)Ks)[idx] = *(const float4*)&kv[basekv + (size_t)kk*256 + i4];
    ((float4*)Vs)[idx] = *(const float4*)&kv[basekv + (size_t)kk*256 + 128 + i4];
  }
  __syncthreads();
  int r = t & 511, g = t >> 9;
  float qr[16];
  #pragma unroll
  for(int i4=0;i4<4;i4++){
    float4 qv = *(const float4*)&qg[baseq + (size_t)r*DDv + i4*4];
    qr[i4*4+0]=qv.x; qr[i4*4+1]=qv.y; qr[i4*4+2]=qv.z; qr[i4*4+3]=qv.w;
  }
  float m = -FLT_MAX, l = 0.f;
  float acc[16] = {};
  int k0 = g*256;
  for(int kk=k0; kk<k0+256; kk++){
    const float* kp = &Ks[kk*16];
    float s = 0.f;
    #pragma unroll
    for(int i=0;i<16;i++) s = fmaf(qr[i], kp[i], s);
    s *= 0.25f;
    if(s > m){                               // rare after warm-up
      float c = __expf(m - s);
      l *= c;
      #pragma unroll
      for(int i=0;i<16;i++) acc[i] *= c;
      m = s;
    }
    float p = __expf(s - m);
    l += p;
    const float* vp = &Vs[kk*16];
    #pragma unroll
    for(int i=0;i<16;i++) acc[i] = fmaf(p, vp[i], acc[i]);
  }
  __syncthreads();                           // K/V consumption complete
  if(g == 1){                                // publish partial state
    #pragma unroll
    for(int i=0;i<16;i++) Ks[r*16 + i] = acc[i];
    Vs[r] = m; Vs[512 + r] = l;
  }
  __syncthreads();
  if(g == 0){                                // exact two-state merge
    float m1 = Vs[r], l1 = Vs[512 + r];
    float M = fmaxf(m, m1);
    float c0 = __expf(m - M), c1 = __expf(m1 - M);
    float inv = 1.0f/(l*c0 + l1*c1);
    #pragma unroll
    for(int i=0;i<16;i++)
      og[baseq + (size_t)r*DDv + i] = (acc[i]*c0 + Ks[r*16 + i]*c1)*inv;
  }
}

// ---- residual + LayerNorm: wave per row, shuffle-reduced, fp32 ----
__global__ __launch_bounds__(256) void ln_k(const float* h, const float* delta,
                                            const void* g, int gdi, const void* bb, int bdi, int po,
                                            float* dst, const int* DF){
  int gf32 = DF[gdi], bf32 = DF[bdi];
  int row = blockIdx.x*4 + (threadIdx.x >> 6);
  int lane = threadIdx.x & 63;
  const float2* hr = (const float2*)(h + (size_t)row*DDv);
  const float2* dr = (const float2*)(delta + (size_t)row*DDv);
  float2 hv = hr[lane], dv = dr[lane];
  float x0 = hv.x + dv.x, x1 = hv.y + dv.y;
  float mu = wsum(x0 + x1) * (1.0f/DDv);
  float d0 = x0 - mu, d1 = x1 - mu;
  float var = wsum(d0*d0 + d1*d1) * (1.0f/DDv);
  float rs = 1.0f/sqrtf(var + 1e-5f);
  int c0 = lane*2;
  float y0 = d0*rs*ldx(g, po+c0,   gf32) + ldx(bb, po+c0,   bf32);
  float y1 = d1*rs*ldx(g, po+c0+1, gf32) + ldx(bb, po+c0+1, bf32);
  ((float2*)(dst + (size_t)row*DDv))[lane] = make_float2(y0, y1);
}

// ---- enc -> fp32 h ----
__global__ __launch_bounds__(256) void cvt_k(const void* in, float* out, const int* DF){
  int f32 = DF[0];
  int tid = blockIdx.x*256 + threadIdx.x;
  out[tid] = ldx(in, tid, f32);
}

extern "C" void kernel_launch(void* const* d_in, const int* in_sizes, int n_in,
                              void* d_out, int out_size, void* d_ws, size_t ws_size,
                              hipStream_t stream) {
  if(n_in != 18){
    diag_fill_k<<<256, 256, 0, stream>>>((float*)d_out, out_size, 1000.0f);
    return;
  }
  const int expect[18] = {
    BB*MMv*DDv, BB*LLv*MMv, DDv*DDv, DDv, DDv*DDv, DDv,
    NLAY*DDv*DDv, NLAY*DDv*DDv, NLAY*DDv*DDv, NLAY*DDv*DDv,
    NLAY*DDv*DFFv, NLAY*DFFv, NLAY*DFFv*DDv, NLAY*DDv,
    NLAY*DDv, NLAY*DDv, NLAY*DDv, NLAY*DDv
  };
  for(int i=0;i<18;i++){
    if(in_sizes[i] != expect[i]){
      diag_fill_k<<<256, 256, 0, stream>>>((float*)d_out, out_size, 2000.0f + 10.0f*i);
      return;
    }
  }

  const void* enc  = d_in[0];
  const void* xe   = d_in[1];
  const void* c1W  = d_in[2];
  const void* c1b  = d_in[3];
  const void* c2W  = d_in[4];
  const void* c2b  = d_in[5];
  const void* Wq   = d_in[6];
  const void* Wk   = d_in[7];
  const void* Wv   = d_in[8];
  const void* Wo   = d_in[9];
  const void* W1   = d_in[10];
  const void* b1   = d_in[11];
  const void* W2   = d_in[12];
  const void* b2   = d_in[13];
  const void* ln1g = d_in[14];
  const void* ln1b = d_in[15];
  const void* ln2g = d_in[16];
  const void* ln2b = d_in[17];

  char* ws = (char*)d_ws;
  size_t o = 0;
  auto alloc = [&](size_t bytes){ size_t r = o; o = (o + bytes + 255) & ~(size_t)255; return r; };
  double* S64  = (double*)(ws + alloc((size_t)NNODE*8));
  double* R64  = (double*)(ws + alloc((size_t)NNODE*8));
  float* dinv  = (float*)(ws + alloc((size_t)NNODE*4));
  int*   cnt   = (int*)  (ws + alloc((size_t)NNODE*4));
  int*   cursor= (int*)  (ws + alloc((size_t)NNODE*4));
  int*   off   = (int*)  (ws + alloc((size_t)(NNODE+1)*4));
  int*   nbr   = (int*)  (ws + alloc((size_t)TOTE*4));
  int*   esrc  = (int*)  (ws + alloc((size_t)TOTE*4));
  int*   DF    = (int*)  (ws + alloc(256));
  ushort_t* Wth = (ushort_t*)(ws + alloc((size_t)WTOT*2));
  ushort_t* Wtl = (ushort_t*)(ws + alloc((size_t)WTOT*2));
  const size_t ACTF = (size_t)NNODE*DDv*4;   // fp32 activation: 8.39 MB
  float* hF = (float*)(ws + alloc(ACTF));
  float* xg = (float*)(ws + alloc(ACTF));
  float* t0 = (float*)(ws + alloc(ACTF));
  float* t1 = (float*)(ws + alloc(ACTF));
  float* t2 = (float*)(ws + alloc(ACTF));    // t1+t2 contiguous: kv[NNODE][256] / ffn hidden
  float* t3 = (float*)(ws + alloc(ACTF));
  float* kv = t1;                             // 16.78 MB span
  float* fb = t1;                             // ffn hidden; kv dead when ffn runs
  // Xhi/Xlo (graph phase only) overlay hF..t1 — consumed by corrsel before cvt_k writes hF
  ushort_t* Xhi = (ushort_t*)hF;
  ushort_t* Xlo = Xhi + (size_t)BB*MMv*LLv;   // 16.78 MB each
  if(ws_size < o){
    diag_fill_k<<<256, 256, 0, stream>>>((float*)d_out, out_size, 3000.0f);
    return;
  }

  // ---- per-input dtype detection + weight transpose/split prep ----
  P18 pack;
  for(int i=0;i<18;i++){ pack.p[i] = (const ushort_t*)d_in[i]; pack.n[i] = in_sizes[i]; }
  ddet_k<<<18, 256, 0, stream>>>(pack, DF);
  prep_k<<<dim3(8,8,14), dim3(32,8), 0, stream>>>(c1W, c2W, Wq, Wk, Wv, Wo, W1, W2,
                                                  Wth, Wtl, DF);

  // --- graph construction (split-bf16 MFMA corr + hi/lo stats + selection) ---
  split_k<<<dim3(16,16,BB), dim3(32,8), 0, stream>>>(xe, Xhi, Xlo, DF);
  stats2_k<<<NNODE/4, 256, 0, stream>>>(Xhi, Xlo, S64, R64);
  corrsel_k<<<dim3(16, BB), 1024, 0, stream>>>(Xhi, Xlo, S64, R64, nbr, DF);
  hipMemsetAsync(cnt, 0, (size_t)NNODE*4, stream);
  hist_k<<<TOTE/256, 256, 0, stream>>>(nbr, cnt);
  scan_k<<<1, 256, 0, stream>>>(cnt, off, cursor, dinv);
  fill_k<<<TOTE/256, 256, 0, stream>>>(nbr, cursor, esrc);

  // --- GCN (2 layers, fp32 activations, MFMA gemms) ---
  cvt_k<<<NNODE*DDv/256, 256, 0, stream>>>(enc, hF, DF);
  gemm_k<<<dim3(4,256), 256, 0, stream>>>(hF, Wth, Wtl, 0, 2, nullptr, 0, 3, t0, DDv, DDv, 0, DF);
  agg_k<<<NNODE/4, 256, 0, stream>>>(t0, off, esrc, dinv, c1b, 3, t1, DF);
  gemm_k<<<dim3(4,256), 256, 0, stream>>>(t1, Wth, Wtl, 16384, 4, nullptr, 0, 5, t0, DDv, DDv, 0, DF);
  agg_k<<<NNODE/4, 256, 0, stream>>>(t0, off, esrc, dinv, c2b, 5, xg, DF);

  // --- transformer (2 layers; query stream = hF, kv = xg) ---
  for(int l=0; l<NLAY; l++){
    qkv_k<<<dim3(12,256), 256, 0, stream>>>(hF, xg, Wth, Wtl,
                                            32768 + (size_t)l*49152, t0, kv, DF);
    attn_k<<<BB*HHv, 1024, 0, stream>>>(t0, kv, t3);
    gemm_k<<<dim3(4,256), 256, 0, stream>>>(t3, Wth, Wtl, 131072 + (size_t)l*16384, 9, nullptr, 0, 9, t0, DDv, DDv, 0, DF);
    ln_k<<<NNODE/4, 256, 0, stream>>>(hF, t0, ln1g, 14, ln1b, 15, l*DDv, hF, DF);
    gemm_k<<<dim3(8,256), 256, 0, stream>>>(hF, Wth, Wtl, 163840 + (size_t)l*32768, 10, b1, l*DFFv, 11, fb, DDv, DFFv, 1, DF);
    gemm_k<<<dim3(4,256), 256, 0, stream>>>(fb, Wth, Wtl, 229376 + (size_t)l*32768, 12, b2, l*DDv, 13, t0, DFFv, DDv, 0, DF);
    float* dst = (l == NLAY-1) ? (float*)d_out : hF;
    ln_k<<<NNODE/4, 256, 0, stream>>>(hF, t0, ln2g, 16, ln2b, 17, l*DDv, dst, DF);
  }
}